// Round 4
// baseline (296.116 us; speedup 1.0000x reference)
//
#include <hip/hip_runtime.h>
#include <stdint.h>

#define HEADS 12
#define DK 64
#define DM 768
#define BT 2
#define SEQ 2048
#define ROWS (BT*SEQ)

typedef __bf16 bf16x4 __attribute__((ext_vector_type(4)));
typedef __bf16 bf16x8 __attribute__((ext_vector_type(8)));
typedef float f32x4 __attribute__((ext_vector_type(4)));

#define SCL2 0.18033688011112042f  /* (1/8) * log2(e) */

__device__ __forceinline__ float exp2fast(float x) {
#if __has_builtin(__builtin_amdgcn_exp2f)
    return __builtin_amdgcn_exp2f(x);
#else
    return exp2f(x);
#endif
}
__device__ __forceinline__ float log2fast(float x) {
#if __has_builtin(__builtin_amdgcn_logf)
    return __builtin_amdgcn_logf(x);
#else
    return log2f(x);
#endif
}

__device__ __forceinline__ uint16_t f2bf(float f) {
    union { float f; uint32_t u; } v; v.f = f;
    uint32_t u = v.u;
    return (uint16_t)((u + 0x7FFFu + ((u >> 16) & 1u)) >> 16);
}

union U8 { uint16_t u[8]; bf16x8 v; float4 f; };

__device__ __forceinline__ bf16x8 cat44(bf16x4 lo, bf16x4 hi) {
    bf16x8 f;
    f[0] = lo[0]; f[1] = lo[1]; f[2] = lo[2]; f[3] = lo[3];
    f[4] = hi[0]; f[5] = hi[1]; f[6] = hi[2]; f[7] = hi[3];
    return f;
}

// Fragment (16 rows, K=32) from padded row-major LDS tile: two b64 reads.
__device__ __forceinline__ bf16x8 ldfrag(const char* p) {
    bf16x4 lo = *(const bf16x4*)p;
    bf16x4 hi = *(const bf16x4*)(p + 32);
    return cat44(lo, hi);
}

// async global->LDS, 16B per lane. Linear LDS dest (wave-uniform base + lane*16).
typedef __attribute__((address_space(3))) void lds_vp;
typedef const __attribute__((address_space(1))) void gbl_vp;
__device__ __forceinline__ void gload16(const void* g, void* l) {
    __builtin_amdgcn_global_load_lds((gbl_vp*)g, (lds_vp*)l, 16, 0, 0);
}

// ---------------- W [k][n] fp32 -> Wt [n][k] bf16 ----------------
__global__ __launch_bounds__(256) void k_transpose(const float* __restrict__ Wq,
                                                   const float* __restrict__ Wk,
                                                   const float* __restrict__ Wv,
                                                   const float* __restrict__ Wo,
                                                   uint16_t* __restrict__ Wqt,
                                                   uint16_t* __restrict__ Wkt,
                                                   uint16_t* __restrict__ Wvt,
                                                   uint16_t* __restrict__ Wot) {
    __shared__ float t[32][33];
    int z = blockIdx.z;
    const float* W = (z == 0) ? Wq : (z == 1) ? Wk : (z == 2) ? Wv : Wo;
    uint16_t* Wt = (z == 0) ? Wqt : (z == 1) ? Wkt : (z == 2) ? Wvt : Wot;
    int bx = blockIdx.x * 32;
    int by = blockIdx.y * 32;
    int tx = threadIdx.x & 31, ty = threadIdx.x >> 5;
#pragma unroll
    for (int r = 0; r < 32; r += 8)
        t[ty + r][tx] = W[(size_t)(bx + ty + r) * DM + by + tx];
    __syncthreads();
#pragma unroll
    for (int r = 0; r < 32; r += 8)
        Wt[(size_t)(by + ty + r) * DM + bx + tx] = f2bf(t[tx][ty + r]);
}

// ---------------- fused QKV GEMM (fp32 A converted in staging) ----------------
__global__ __launch_bounds__(256) void k_gemm_qkv(const float* __restrict__ Aq,
                                                  const float* __restrict__ Ak,
                                                  const float* __restrict__ Av,
                                                  const uint16_t* __restrict__ Wt,
                                                  const float* __restrict__ bq,
                                                  const float* __restrict__ bk,
                                                  const float* __restrict__ bv,
                                                  uint16_t* __restrict__ Qm,
                                                  uint16_t* __restrict__ Km,
                                                  uint16_t* __restrict__ VT) {
    __shared__ char smem[2 * 2 * 128 * 80];
    const int z = blockIdx.z;
    const float* A = (z == 0) ? Aq : (z == 1) ? Ak : Av;
    const uint16_t* Bt = Wt + (size_t)z * DM * DM;
    const float* bias = (z == 0) ? bq : (z == 1) ? bk : bv;
    const int tid = threadIdx.x, lane = tid & 63, w = tid >> 6;
    const int q = lane >> 4, r16 = lane & 15;
    const int mtile = blockIdx.y * 128, ntile = blockIdx.x * 128;
    const int wm = (w >> 1) * 64, wn = (w & 1) * 64;
    const int srow = tid >> 1, shalf = tid & 1;
    const float* ap = A + (size_t)(mtile + srow) * DM + shalf * 16;
    const uint16_t* bp = Bt + (size_t)(ntile + srow) * DM + shalf * 16;
    f32x4 acc[4][4] = {};
    float4 ra0 = *(const float4*)(ap + 0);
    float4 ra1 = *(const float4*)(ap + 4);
    float4 ra2 = *(const float4*)(ap + 8);
    float4 ra3 = *(const float4*)(ap + 12);
    float4 rb0 = *(const float4*)bp;
    float4 rb1 = *(const float4*)((const char*)bp + 16);
    for (int t = 0; t < 24; ++t) {
        char* As = smem + (t & 1) * 20480;
        char* Bs = As + 10240;
        U8 pk0, pk1;
        pk0.u[0] = f2bf(ra0.x); pk0.u[1] = f2bf(ra0.y); pk0.u[2] = f2bf(ra0.z); pk0.u[3] = f2bf(ra0.w);
        pk0.u[4] = f2bf(ra1.x); pk0.u[5] = f2bf(ra1.y); pk0.u[6] = f2bf(ra1.z); pk0.u[7] = f2bf(ra1.w);
        pk1.u[0] = f2bf(ra2.x); pk1.u[1] = f2bf(ra2.y); pk1.u[2] = f2bf(ra2.z); pk1.u[3] = f2bf(ra2.w);
        pk1.u[4] = f2bf(ra3.x); pk1.u[5] = f2bf(ra3.y); pk1.u[6] = f2bf(ra3.z); pk1.u[7] = f2bf(ra3.w);
        *(float4*)(As + srow * 80 + shalf * 32) = pk0.f;
        *(float4*)(As + srow * 80 + shalf * 32 + 16) = pk1.f;
        *(float4*)(Bs + srow * 80 + shalf * 32) = rb0;
        *(float4*)(Bs + srow * 80 + shalf * 32 + 16) = rb1;
        if (t < 23) {
            const float* ap2 = ap + (t + 1) * 32;
            ra0 = *(const float4*)(ap2 + 0);
            ra1 = *(const float4*)(ap2 + 4);
            ra2 = *(const float4*)(ap2 + 8);
            ra3 = *(const float4*)(ap2 + 12);
            const uint16_t* bp2 = bp + (t + 1) * 32;
            rb0 = *(const float4*)bp2;
            rb1 = *(const float4*)((const char*)bp2 + 16);
        }
        __syncthreads();
        bf16x8 af[4], bfr[4];
#pragma unroll
        for (int i = 0; i < 4; i++) {
            af[i] = ldfrag(As + (wm + i * 16 + r16) * 80 + q * 8);
            bfr[i] = ldfrag(Bs + (wn + i * 16 + r16) * 80 + q * 8);
        }
#pragma unroll
        for (int mi = 0; mi < 4; mi++)
#pragma unroll
            for (int ni = 0; ni < 4; ni++)
                acc[mi][ni] = __builtin_amdgcn_mfma_f32_16x16x32_bf16(
                    af[mi], bfr[ni], acc[mi][ni], 0, 0, 0);
    }
    if (z < 2) {
        uint16_t* out = (z == 0) ? Qm : Km;
#pragma unroll
        for (int ni = 0; ni < 4; ni++) {
            int n = ntile + wn + ni * 16 + r16;
            float bv2 = bias[n];
#pragma unroll
            for (int mi = 0; mi < 4; mi++)
#pragma unroll
                for (int r = 0; r < 4; r++) {
                    int m = mtile + wm + mi * 16 + 4 * q + r;
                    out[(size_t)m * DM + n] = f2bf(acc[mi][ni][r] + bv2);
                }
        }
    } else {
#pragma unroll
        for (int ni = 0; ni < 4; ni++) {
            int n = ntile + wn + ni * 16 + r16;
            int h = n >> 6, dk = n & 63;
            float bv2 = bias[n];
#pragma unroll
            for (int mi = 0; mi < 4; mi++) {
                int mbase = mtile + wm + mi * 16 + 4 * q;
                int b = mbase >> 11, s = mbase & 2047;
                ushort4 o;
                o.x = f2bf(acc[mi][ni][0] + bv2);
                o.y = f2bf(acc[mi][ni][1] + bv2);
                o.z = f2bf(acc[mi][ni][2] + bv2);
                o.w = f2bf(acc[mi][ni][3] + bv2);
                *(ushort4*)(VT + ((size_t)((b * HEADS + h) * DK + dk)) * SEQ + s) = o;
            }
        }
    }
}

// ---------------- output GEMM (bf16 A, fp32 out) ----------------
__global__ __launch_bounds__(256) void k_gemm_o(const uint16_t* __restrict__ A,
                                                const uint16_t* __restrict__ Bt,
                                                const float* __restrict__ bias,
                                                float* __restrict__ C) {
    __shared__ char smem[2 * 2 * 128 * 80];
    const int tid = threadIdx.x, lane = tid & 63, w = tid >> 6;
    const int q = lane >> 4, r16 = lane & 15;
    const int mtile = blockIdx.y * 128, ntile = blockIdx.x * 128;
    const int wm = (w >> 1) * 64, wn = (w & 1) * 64;
    const int srow = tid >> 1, shalf = tid & 1;
    const uint16_t* ap = A + (size_t)(mtile + srow) * DM + shalf * 16;
    const uint16_t* bp = Bt + (size_t)(ntile + srow) * DM + shalf * 16;
    f32x4 acc[4][4] = {};
    float4 ra0 = *(const float4*)ap;
    float4 ra1 = *(const float4*)((const char*)ap + 16);
    float4 rb0 = *(const float4*)bp;
    float4 rb1 = *(const float4*)((const char*)bp + 16);
    for (int t = 0; t < 24; ++t) {
        char* As = smem + (t & 1) * 20480;
        char* Bs = As + 10240;
        *(float4*)(As + srow * 80 + shalf * 32) = ra0;
        *(float4*)(As + srow * 80 + shalf * 32 + 16) = ra1;
        *(float4*)(Bs + srow * 80 + shalf * 32) = rb0;
        *(float4*)(Bs + srow * 80 + shalf * 32 + 16) = rb1;
        if (t < 23) {
            const uint16_t* ap2 = ap + (t + 1) * 32;
            ra0 = *(const float4*)ap2;
            ra1 = *(const float4*)((const char*)ap2 + 16);
            const uint16_t* bp2 = bp + (t + 1) * 32;
            rb0 = *(const float4*)bp2;
            rb1 = *(const float4*)((const char*)bp2 + 16);
        }
        __syncthreads();
        bf16x8 af[4], bfr[4];
#pragma unroll
        for (int i = 0; i < 4; i++) {
            af[i] = ldfrag(As + (wm + i * 16 + r16) * 80 + q * 8);
            bfr[i] = ldfrag(Bs + (wn + i * 16 + r16) * 80 + q * 8);
        }
#pragma unroll
        for (int mi = 0; mi < 4; mi++)
#pragma unroll
            for (int ni = 0; ni < 4; ni++)
                acc[mi][ni] = __builtin_amdgcn_mfma_f32_16x16x32_bf16(
                    af[mi], bfr[ni], acc[mi][ni], 0, 0, 0);
    }
#pragma unroll
    for (int ni = 0; ni < 4; ni++) {
        int n = ntile + wn + ni * 16 + r16;
        float bv = bias[n];
#pragma unroll
        for (int mi = 0; mi < 4; mi++)
#pragma unroll
            for (int r = 0; r < 4; r++) {
                int m = mtile + wm + mi * 16 + 4 * q + r;
                C[(size_t)m * DM + n] = acc[mi][ni][r] + bv;
            }
    }
}

// ---------------- pass 1: L2[j] = -log2( sum_i 2^(s2[i][j]) ) ----------------
// 2 waves x 64 j (K in regs); Q streamed via global_load_lds, XOR-swizzled.
__global__ __launch_bounds__(128, 2) void k_stats(const uint16_t* __restrict__ Qm,
                                                  const uint16_t* __restrict__ Km,
                                                  float* __restrict__ L2buf) {
    __shared__ char lds[2 * 8192];
    const int tid = threadIdx.x, lane = tid & 63;
    const int w = tid >> 6;
    const int q = lane >> 4, r16 = lane & 15;
    const int bh = blockIdx.y, b = bh / HEADS, h = bh % HEADS;
    const int j0 = blockIdx.x * 128 + w * 64;
    const uint16_t* Qbase = Qm + (size_t)b * SEQ * DM + h * DK;
    // K fragments (A operand) direct from global, held in regs
    bf16x8 kf[4][2];
#pragma unroll
    for (int jf = 0; jf < 4; jf++) {
        const uint16_t* kp = Km + (size_t)(b * SEQ + j0 + jf * 16 + r16) * DM + h * DK + q * 4;
#pragma unroll
        for (int ks = 0; ks < 2; ks++)
            kf[jf][ks] = cat44(*(const bf16x4*)(kp + ks * 32),
                               *(const bf16x4*)(kp + ks * 32 + 16));
    }
    float Zs[4][4] = {};
    // prologue stage tile 0
#pragma unroll
    for (int c = 0; c < 4; c++) {
        int n = c * 128 + tid, row = n >> 3, u = n & 7;
        gload16(Qbase + (size_t)row * DM + ((u ^ (row & 7)) * 8), lds + n * 16);
    }
    for (int t = 0; t < 32; ++t) {
        asm volatile("s_waitcnt vmcnt(0)" ::: "memory");
        __builtin_amdgcn_s_barrier();
        if (t < 31) {
            char* nb = lds + ((t + 1) & 1) * 8192;
            int i1 = (t + 1) * 64;
#pragma unroll
            for (int c = 0; c < 4; c++) {
                int n = c * 128 + tid, row = n >> 3, u = n & 7;
                gload16(Qbase + (size_t)(i1 + row) * DM + ((u ^ (row & 7)) * 8), nb + n * 16);
            }
        }
        const char* Qs = lds + (t & 1) * 8192;
#pragma unroll
        for (int f = 0; f < 4; f++) {
            bf16x8 qfr[2];
#pragma unroll
            for (int ks = 0; ks < 2; ks++) {
                int row = f * 16 + r16;
                int ulo = (ks * 4 + (q >> 1)) ^ (row & 7);
                int uhi = (ks * 4 + 2 + (q >> 1)) ^ (row & 7);
                qfr[ks] = cat44(*(const bf16x4*)(Qs + row * 128 + ulo * 16 + (q & 1) * 8),
                                *(const bf16x4*)(Qs + row * 128 + uhi * 16 + (q & 1) * 8));
            }
            f32x4 st[4] = {};
#pragma unroll
            for (int jf = 0; jf < 4; jf++)
#pragma unroll
                for (int ks = 0; ks < 2; ks++)
                    st[jf] = __builtin_amdgcn_mfma_f32_16x16x32_bf16(kf[jf][ks], qfr[ks], st[jf], 0, 0, 0);
#pragma unroll
            for (int jf = 0; jf < 4; jf++)
#pragma unroll
                for (int r = 0; r < 4; r++)
                    Zs[jf][r] += exp2fast(st[jf][r] * SCL2);
        }
    }
#pragma unroll
    for (int jf = 0; jf < 4; jf++)
#pragma unroll
        for (int r = 0; r < 4; r++) {
            float e = Zs[jf][r];
#pragma unroll
            for (int m = 1; m < 16; m <<= 1) e += __shfl_xor(e, m);
            if (r16 == 0)
                L2buf[(size_t)bh * SEQ + j0 + jf * 16 + 4 * q + r] = -log2fast(e);
        }
}

// ---------------- pass 2: X = P @ V, P = 2^(s2 + L2[j]); I=64/wave ----------------
__global__ __launch_bounds__(128, 2) void k_attn(const uint16_t* __restrict__ Qm,
                                                 const uint16_t* __restrict__ Km,
                                                 const uint16_t* __restrict__ VT,
                                                 const float* __restrict__ L2,
                                                 uint16_t* __restrict__ Xm) {
    __shared__ char lds[2 * 16384];  // [buf][ K 8KB | V^T 8KB ], 16B-unit XOR-swizzled
    const int tid = threadIdx.x, lane = tid & 63, w = tid >> 6;
    const int q = lane >> 4, r16 = lane & 15;
    const int bh = blockIdx.y, b = bh / HEADS, h = bh % HEADS;
    const int i0 = blockIdx.x * 128 + w * 64;
    const uint16_t* Qbase = Qm + (size_t)b * SEQ * DM + h * DK;
    const uint16_t* Kbase = Km + (size_t)b * SEQ * DM + h * DK;
    const uint16_t* VTb = VT + (size_t)bh * DK * SEQ;
    const float* L2b = L2 + (size_t)bh * SEQ;
    // Q fragments (B operand), 4 i-groups, direct from global
    bf16x8 qf[4][2];
#pragma unroll
    for (int ig = 0; ig < 4; ig++) {
        const uint16_t* qp = Qbase + (size_t)(i0 + ig * 16 + r16) * DM + q * 4;
#pragma unroll
        for (int ks = 0; ks < 2; ks++)
            qf[ig][ks] = cat44(*(const bf16x4*)(qp + ks * 32),
                               *(const bf16x4*)(qp + ks * 32 + 16));
    }
    f32x4 xacc[4][4] = {};  // [dc][ig]
    // prologue stage tile 0 (K then V)
#pragma unroll
    for (int c = 0; c < 4; c++) {
        int n = c * 128 + tid, row = n >> 3, u = n & 7;
        gload16(Kbase + (size_t)row * DM + ((u ^ (row & 7)) * 8), lds + n * 16);
        gload16(VTb + (size_t)row * SEQ + ((u ^ (row & 7)) * 8), lds + 8192 + n * 16);
    }
    for (int t = 0; t < 32; ++t) {
        asm volatile("s_waitcnt vmcnt(0)" ::: "memory");
        __builtin_amdgcn_s_barrier();
        if (t < 31) {
            char* nb = lds + ((t + 1) & 1) * 16384;
            int js1 = (t + 1) * 64;
#pragma unroll
            for (int c = 0; c < 4; c++) {
                int n = c * 128 + tid, row = n >> 3, u = n & 7;
                gload16(Kbase + (size_t)(js1 + row) * DM + ((u ^ (row & 7)) * 8), nb + n * 16);
                gload16(VTb + (size_t)row * SEQ + js1 + ((u ^ (row & 7)) * 8), nb + 8192 + n * 16);
            }
        }
        const char* Ks = lds + (t & 1) * 16384;
        const char* Vs = Ks + 8192;
        const int js = t * 64;
        // K fragments (A operand, rows j), read once, reused by 4 i-groups
        bf16x8 kf[4][2], vf[4][2];
#pragma unroll
        for (int jf = 0; jf < 4; jf++)
#pragma unroll
            for (int ks = 0; ks < 2; ks++) {
                int row = jf * 16 + r16;
                int ulo = (ks * 4 + (q >> 1)) ^ (row & 7);
                int uhi = (ks * 4 + 2 + (q >> 1)) ^ (row & 7);
                kf[jf][ks] = cat44(*(const bf16x4*)(Ks + row * 128 + ulo * 16 + (q & 1) * 8),
                                   *(const bf16x4*)(Ks + row * 128 + uhi * 16 + (q & 1) * 8));
            }
#pragma unroll
        for (int dc = 0; dc < 4; dc++)
#pragma unroll
            for (int c = 0; c < 2; c++) {
                int row = dc * 16 + r16;
                int ulo = (c * 4 + (q >> 1)) ^ (row & 7);
                int uhi = (c * 4 + 2 + (q >> 1)) ^ (row & 7);
                vf[dc][c] = cat44(*(const bf16x4*)(Vs + row * 128 + ulo * 16 + (q & 1) * 8),
                                  *(const bf16x4*)(Vs + row * 128 + uhi * 16 + (q & 1) * 8));
            }
        float l2v[4][4];
#pragma unroll
        for (int jf = 0; jf < 4; jf++) {
            float4 lv = *(const float4*)(L2b + js + jf * 16 + 4 * q);
            l2v[jf][0] = lv.x; l2v[jf][1] = lv.y; l2v[jf][2] = lv.z; l2v[jf][3] = lv.w;
        }
#pragma unroll
        for (int ig = 0; ig < 4; ig++) {
            f32x4 st[4] = {};
#pragma unroll
            for (int jf = 0; jf < 4; jf++)
#pragma unroll
                for (int ks = 0; ks < 2; ks++)
                    st[jf] = __builtin_amdgcn_mfma_f32_16x16x32_bf16(kf[jf][ks], qf[ig][ks], st[jf], 0, 0, 0);
            bf16x8 pb[2];
#pragma unroll
            for (int c = 0; c < 2; c++) {
                U8 t8;
#pragma unroll
                for (int r = 0; r < 4; r++) {
                    t8.u[r]     = f2bf(exp2fast(st[2 * c][r] * SCL2 + l2v[2 * c][r]));
                    t8.u[4 + r] = f2bf(exp2fast(st[2 * c + 1][r] * SCL2 + l2v[2 * c + 1][r]));
                }
                pb[c] = t8.v;
            }
#pragma unroll
            for (int dc = 0; dc < 4; dc++)
#pragma unroll
                for (int c = 0; c < 2; c++)
                    xacc[dc][ig] = __builtin_amdgcn_mfma_f32_16x16x32_bf16(vf[dc][c], pb[c], xacc[dc][ig], 0, 0, 0);
        }
    }
    __syncthreads();
    // epilogue: X^T (d,i) -> X (i,d) via per-wave LDS region [64 i][144B]
    char* xr = lds + w * 9216;
#pragma unroll
    for (int dc = 0; dc < 4; dc++)
#pragma unroll
        for (int ig = 0; ig < 4; ig++) {
            bf16x4 pk;
            pk[0] = (__bf16)xacc[dc][ig][0];
            pk[1] = (__bf16)xacc[dc][ig][1];
            pk[2] = (__bf16)xacc[dc][ig][2];
            pk[3] = (__bf16)xacc[dc][ig][3];
            *(bf16x4*)(xr + (ig * 16 + r16) * 144 + (dc * 16 + 4 * q) * 2) = pk;
        }
    __syncthreads();
#pragma unroll
    for (int rr = 0; rr < 8; rr++) {
        int row = rr * 8 + (lane >> 3), seg = lane & 7;
        *(float4*)(Xm + (size_t)(b * SEQ + i0 + row) * DM + h * DK + seg * 8) =
            *(const float4*)(xr + row * 144 + seg * 16);
    }
}

extern "C" void kernel_launch(void* const* d_in, const int* in_sizes, int n_in,
                              void* d_out, int out_size, void* d_ws, size_t ws_size,
                              hipStream_t stream) {
    const float* query = (const float*)d_in[0];
    const float* key = (const float*)d_in[1];
    const float* value = (const float*)d_in[2];
    const float* Wq = (const float*)d_in[3];
    const float* bq = (const float*)d_in[4];
    const float* Wk = (const float*)d_in[5];
    const float* bk = (const float*)d_in[6];
    const float* Wv = (const float*)d_in[7];
    const float* bv = (const float*)d_in[8];
    const float* Wo = (const float*)d_in[9];
    const float* bo = (const float*)d_in[10];
    float* out = (float*)d_out;
    char* ws = (char*)d_ws;

    const size_t SZ = (size_t)ROWS * DM * 2;
    const size_t WSZ = (size_t)DM * DM * 2;
    uint16_t* Qm = (uint16_t*)(ws + 0 * SZ);
    uint16_t* Km = (uint16_t*)(ws + 1 * SZ);
    uint16_t* VT = (uint16_t*)(ws + 2 * SZ);
    uint16_t* Xm = (uint16_t*)(ws + 3 * SZ);
    uint16_t* Wqt = (uint16_t*)(ws + 4 * SZ);
    uint16_t* Wkt = (uint16_t*)(ws + 4 * SZ + WSZ);
    uint16_t* Wvt = (uint16_t*)(ws + 4 * SZ + 2 * WSZ);
    uint16_t* Wot = (uint16_t*)(ws + 4 * SZ + 3 * WSZ);
    float* L2buf = (float*)(ws + 4 * SZ + 4 * WSZ);

    k_transpose<<<dim3(24, 24, 4), 256, 0, stream>>>(Wq, Wk, Wv, Wo, Wqt, Wkt, Wvt, Wot);
    k_gemm_qkv<<<dim3(6, 32, 3), 256, 0, stream>>>(query, key, value, Wqt, bq, bk, bv, Qm, Km, VT);
    k_stats<<<dim3(16, 24), 128, 0, stream>>>(Qm, Km, L2buf);
    k_attn<<<dim3(16, 24), 128, 0, stream>>>(Qm, Km, VT, L2buf, Xm);
    k_gemm_o<<<dim3(6, 32), 256, 0, stream>>>(Xm, Wot, bo, out);
}

// Round 5
// 256.168 us; speedup vs baseline: 1.1559x; 1.1559x over previous
//
#include <hip/hip_runtime.h>
#include <stdint.h>

#define HEADS 12
#define DK 64
#define DM 768
#define BT 2
#define SEQ 2048
#define ROWS (BT*SEQ)

typedef __bf16 bf16x4 __attribute__((ext_vector_type(4)));
typedef __bf16 bf16x8 __attribute__((ext_vector_type(8)));
typedef float f32x4 __attribute__((ext_vector_type(4)));

#define SCL2 0.18033688011112042f  /* (1/8) * log2(e) */

__device__ __forceinline__ float exp2fast(float x) {
#if __has_builtin(__builtin_amdgcn_exp2f)
    return __builtin_amdgcn_exp2f(x);
#else
    return exp2f(x);
#endif
}
__device__ __forceinline__ float log2fast(float x) {
#if __has_builtin(__builtin_amdgcn_logf)
    return __builtin_amdgcn_logf(x);
#else
    return log2f(x);
#endif
}

__device__ __forceinline__ uint16_t f2bf(float f) {
    union { float f; uint32_t u; } v; v.f = f;
    uint32_t u = v.u;
    return (uint16_t)((u + 0x7FFFu + ((u >> 16) & 1u)) >> 16);
}

union U8 { uint16_t u[8]; bf16x8 v; float4 f; };

__device__ __forceinline__ bf16x8 cat44(bf16x4 lo, bf16x4 hi) {
    bf16x8 f;
    f[0] = lo[0]; f[1] = lo[1]; f[2] = lo[2]; f[3] = lo[3];
    f[4] = hi[0]; f[5] = hi[1]; f[6] = hi[2]; f[7] = hi[3];
    return f;
}

__device__ __forceinline__ bf16x8 ldfrag(const char* p) {
    bf16x4 lo = *(const bf16x4*)p;
    bf16x4 hi = *(const bf16x4*)(p + 32);
    return cat44(lo, hi);
}

// Fragment read from a [rows][128B] XOR-swizzled LDS tile (16B unit u stored at u^(row&7)).
__device__ __forceinline__ bf16x8 ldswz(const char* base, int row, int ks, int q) {
    int ulo = (ks * 4 + (q >> 1)) ^ (row & 7);
    int uhi = (ks * 4 + 2 + (q >> 1)) ^ (row & 7);
    return cat44(*(const bf16x4*)(base + row * 128 + ulo * 16 + (q & 1) * 8),
                 *(const bf16x4*)(base + row * 128 + uhi * 16 + (q & 1) * 8));
}

// async global->LDS, 16B per lane; per-lane LDS addr must be waveuniform + lane*16.
typedef __attribute__((address_space(3))) void lds_vp;
typedef const __attribute__((address_space(1))) void gbl_vp;
__device__ __forceinline__ void gload16(const void* g, void* l) {
    __builtin_amdgcn_global_load_lds((gbl_vp*)g, (lds_vp*)l, 16, 0, 0);
}

// ---------------- W [k][n] fp32 -> Wt [n][k] bf16 ----------------
__global__ __launch_bounds__(256) void k_transpose(const float* __restrict__ Wq,
                                                   const float* __restrict__ Wk,
                                                   const float* __restrict__ Wv,
                                                   const float* __restrict__ Wo,
                                                   uint16_t* __restrict__ Wqt,
                                                   uint16_t* __restrict__ Wkt,
                                                   uint16_t* __restrict__ Wvt,
                                                   uint16_t* __restrict__ Wot) {
    __shared__ float t[32][33];
    int z = blockIdx.z;
    const float* W = (z == 0) ? Wq : (z == 1) ? Wk : (z == 2) ? Wv : Wo;
    uint16_t* Wt = (z == 0) ? Wqt : (z == 1) ? Wkt : (z == 2) ? Wvt : Wot;
    int bx = blockIdx.x * 32;
    int by = blockIdx.y * 32;
    int tx = threadIdx.x & 31, ty = threadIdx.x >> 5;
#pragma unroll
    for (int r = 0; r < 32; r += 8)
        t[ty + r][tx] = W[(size_t)(bx + ty + r) * DM + by + tx];
    __syncthreads();
#pragma unroll
    for (int r = 0; r < 32; r += 8)
        Wt[(size_t)(by + ty + r) * DM + bx + tx] = f2bf(t[tx][ty + r]);
}

// ---------------- fused QKV GEMM (fp32 A converted in staging) ----------------
__global__ __launch_bounds__(256) void k_gemm_qkv(const float* __restrict__ Aq,
                                                  const float* __restrict__ Ak,
                                                  const float* __restrict__ Av,
                                                  const uint16_t* __restrict__ Wt,
                                                  const float* __restrict__ bq,
                                                  const float* __restrict__ bk,
                                                  const float* __restrict__ bv,
                                                  uint16_t* __restrict__ Qm,
                                                  uint16_t* __restrict__ Km,
                                                  uint16_t* __restrict__ VT) {
    __shared__ char smem[2 * 2 * 128 * 80];
    const int z = blockIdx.z;
    const float* A = (z == 0) ? Aq : (z == 1) ? Ak : Av;
    const uint16_t* Bt = Wt + (size_t)z * DM * DM;
    const float* bias = (z == 0) ? bq : (z == 1) ? bk : bv;
    const int tid = threadIdx.x, lane = tid & 63, w = tid >> 6;
    const int q = lane >> 4, r16 = lane & 15;
    const int mtile = blockIdx.y * 128, ntile = blockIdx.x * 128;
    const int wm = (w >> 1) * 64, wn = (w & 1) * 64;
    const int srow = tid >> 1, shalf = tid & 1;
    const float* ap = A + (size_t)(mtile + srow) * DM + shalf * 16;
    const uint16_t* bp = Bt + (size_t)(ntile + srow) * DM + shalf * 16;
    f32x4 acc[4][4] = {};
    float4 ra0 = *(const float4*)(ap + 0);
    float4 ra1 = *(const float4*)(ap + 4);
    float4 ra2 = *(const float4*)(ap + 8);
    float4 ra3 = *(const float4*)(ap + 12);
    float4 rb0 = *(const float4*)bp;
    float4 rb1 = *(const float4*)((const char*)bp + 16);
    for (int t = 0; t < 24; ++t) {
        char* As = smem + (t & 1) * 20480;
        char* Bs = As + 10240;
        U8 pk0, pk1;
        pk0.u[0] = f2bf(ra0.x); pk0.u[1] = f2bf(ra0.y); pk0.u[2] = f2bf(ra0.z); pk0.u[3] = f2bf(ra0.w);
        pk0.u[4] = f2bf(ra1.x); pk0.u[5] = f2bf(ra1.y); pk0.u[6] = f2bf(ra1.z); pk0.u[7] = f2bf(ra1.w);
        pk1.u[0] = f2bf(ra2.x); pk1.u[1] = f2bf(ra2.y); pk1.u[2] = f2bf(ra2.z); pk1.u[3] = f2bf(ra2.w);
        pk1.u[4] = f2bf(ra3.x); pk1.u[5] = f2bf(ra3.y); pk1.u[6] = f2bf(ra3.z); pk1.u[7] = f2bf(ra3.w);
        *(float4*)(As + srow * 80 + shalf * 32) = pk0.f;
        *(float4*)(As + srow * 80 + shalf * 32 + 16) = pk1.f;
        *(float4*)(Bs + srow * 80 + shalf * 32) = rb0;
        *(float4*)(Bs + srow * 80 + shalf * 32 + 16) = rb1;
        if (t < 23) {
            const float* ap2 = ap + (t + 1) * 32;
            ra0 = *(const float4*)(ap2 + 0);
            ra1 = *(const float4*)(ap2 + 4);
            ra2 = *(const float4*)(ap2 + 8);
            ra3 = *(const float4*)(ap2 + 12);
            const uint16_t* bp2 = bp + (t + 1) * 32;
            rb0 = *(const float4*)bp2;
            rb1 = *(const float4*)((const char*)bp2 + 16);
        }
        __syncthreads();
        bf16x8 af[4], bfr[4];
#pragma unroll
        for (int i = 0; i < 4; i++) {
            af[i] = ldfrag(As + (wm + i * 16 + r16) * 80 + q * 8);
            bfr[i] = ldfrag(Bs + (wn + i * 16 + r16) * 80 + q * 8);
        }
#pragma unroll
        for (int mi = 0; mi < 4; mi++)
#pragma unroll
            for (int ni = 0; ni < 4; ni++)
                acc[mi][ni] = __builtin_amdgcn_mfma_f32_16x16x32_bf16(
                    af[mi], bfr[ni], acc[mi][ni], 0, 0, 0);
    }
    if (z < 2) {
        uint16_t* out = (z == 0) ? Qm : Km;
#pragma unroll
        for (int ni = 0; ni < 4; ni++) {
            int n = ntile + wn + ni * 16 + r16;
            float bv2 = bias[n];
#pragma unroll
            for (int mi = 0; mi < 4; mi++)
#pragma unroll
                for (int r = 0; r < 4; r++) {
                    int m = mtile + wm + mi * 16 + 4 * q + r;
                    out[(size_t)m * DM + n] = f2bf(acc[mi][ni][r] + bv2);
                }
        }
    } else {
#pragma unroll
        for (int ni = 0; ni < 4; ni++) {
            int n = ntile + wn + ni * 16 + r16;
            int h = n >> 6, dk = n & 63;
            float bv2 = bias[n];
#pragma unroll
            for (int mi = 0; mi < 4; mi++) {
                int mbase = mtile + wm + mi * 16 + 4 * q;
                int b = mbase >> 11, s = mbase & 2047;
                ushort4 o;
                o.x = f2bf(acc[mi][ni][0] + bv2);
                o.y = f2bf(acc[mi][ni][1] + bv2);
                o.z = f2bf(acc[mi][ni][2] + bv2);
                o.w = f2bf(acc[mi][ni][3] + bv2);
                *(ushort4*)(VT + ((size_t)((b * HEADS + h) * DK + dk)) * SEQ + s) = o;
            }
        }
    }
}

// ---------------- output GEMM (bf16 A, fp32 out) ----------------
__global__ __launch_bounds__(256) void k_gemm_o(const uint16_t* __restrict__ A,
                                                const uint16_t* __restrict__ Bt,
                                                const float* __restrict__ bias,
                                                float* __restrict__ C) {
    __shared__ char smem[2 * 2 * 128 * 80];
    const int tid = threadIdx.x, lane = tid & 63, w = tid >> 6;
    const int q = lane >> 4, r16 = lane & 15;
    const int mtile = blockIdx.y * 128, ntile = blockIdx.x * 128;
    const int wm = (w >> 1) * 64, wn = (w & 1) * 64;
    const int srow = tid >> 1, shalf = tid & 1;
    const uint16_t* ap = A + (size_t)(mtile + srow) * DM + shalf * 16;
    const uint16_t* bp = Bt + (size_t)(ntile + srow) * DM + shalf * 16;
    f32x4 acc[4][4] = {};
    float4 ra0 = *(const float4*)ap;
    float4 ra1 = *(const float4*)((const char*)ap + 16);
    float4 rb0 = *(const float4*)bp;
    float4 rb1 = *(const float4*)((const char*)bp + 16);
    for (int t = 0; t < 24; ++t) {
        char* As = smem + (t & 1) * 20480;
        char* Bs = As + 10240;
        *(float4*)(As + srow * 80 + shalf * 32) = ra0;
        *(float4*)(As + srow * 80 + shalf * 32 + 16) = ra1;
        *(float4*)(Bs + srow * 80 + shalf * 32) = rb0;
        *(float4*)(Bs + srow * 80 + shalf * 32 + 16) = rb1;
        if (t < 23) {
            const uint16_t* ap2 = ap + (t + 1) * 32;
            ra0 = *(const float4*)ap2;
            ra1 = *(const float4*)((const char*)ap2 + 16);
            const uint16_t* bp2 = bp + (t + 1) * 32;
            rb0 = *(const float4*)bp2;
            rb1 = *(const float4*)((const char*)bp2 + 16);
        }
        __syncthreads();
        bf16x8 af[4], bfr[4];
#pragma unroll
        for (int i = 0; i < 4; i++) {
            af[i] = ldfrag(As + (wm + i * 16 + r16) * 80 + q * 8);
            bfr[i] = ldfrag(Bs + (wn + i * 16 + r16) * 80 + q * 8);
        }
#pragma unroll
        for (int mi = 0; mi < 4; mi++)
#pragma unroll
            for (int ni = 0; ni < 4; ni++)
                acc[mi][ni] = __builtin_amdgcn_mfma_f32_16x16x32_bf16(
                    af[mi], bfr[ni], acc[mi][ni], 0, 0, 0);
    }
#pragma unroll
    for (int ni = 0; ni < 4; ni++) {
        int n = ntile + wn + ni * 16 + r16;
        float bv = bias[n];
#pragma unroll
        for (int mi = 0; mi < 4; mi++)
#pragma unroll
            for (int r = 0; r < 4; r++) {
                int m = mtile + wm + mi * 16 + 4 * q + r;
                C[(size_t)m * DM + n] = acc[mi][ni][r] + bv;
            }
    }
}

// ---------------- pass 1: L2[j] = -log2( sum_i 2^(s2[i][j]) ) ----------------
// 4 waves x 32 j (K frags in regs, extracted from a staged LDS block);
// Q streamed via global_load_lds, 2-deep counted-vmcnt pipeline, 4 buffers.
__global__ __launch_bounds__(256, 4) void k_stats(const uint16_t* __restrict__ Qm,
                                                  const uint16_t* __restrict__ Km,
                                                  float* __restrict__ L2buf) {
    __shared__ char lds[4 * 8192];
    const int tid = threadIdx.x, lane = tid & 63, w = tid >> 6;
    const int q = lane >> 4, r16 = lane & 15;
    const int bh = blockIdx.y, b = bh / HEADS, h = bh % HEADS;
    const int j0 = blockIdx.x * 128 + w * 32;
    const uint16_t* Qbase = Qm + (size_t)b * SEQ * DM + h * DK;
    const uint16_t* Kbase = Km + (size_t)(b * SEQ + blockIdx.x * 128) * DM + h * DK;

    // stage block's K rows [128][128B] swizzled, extract kf, then free the space
#pragma unroll
    for (int c = 0; c < 4; c++) {
        int n = c * 256 + tid, row = n >> 3, u = n & 7;
        gload16(Kbase + (size_t)row * DM + ((u ^ (row & 7)) * 8), lds + n * 16);
    }
    asm volatile("s_waitcnt vmcnt(0)" ::: "memory");
    __syncthreads();
    bf16x8 kf[2][2];
#pragma unroll
    for (int jf = 0; jf < 2; jf++)
#pragma unroll
        for (int ks = 0; ks < 2; ks++)
            kf[jf][ks] = ldswz(lds, w * 32 + jf * 16 + r16, ks, q);
    __syncthreads();

    // pipeline Q tiles (64 i x 128B = 8KB, 2 loads/thread)
    auto stage = [&](int tt) {
        char* buf = lds + (tt & 3) * 8192;
        int i1 = (tt & 31) * 64;
#pragma unroll
        for (int c = 0; c < 2; c++) {
            int n = c * 256 + tid, row = n >> 3, u = n & 7;
            gload16(Qbase + (size_t)(i1 + row) * DM + ((u ^ (row & 7)) * 8), buf + n * 16);
        }
    };
    stage(0); stage(1);
    float Zs[2][4] = {};
    for (int t = 0; t < 32; ++t) {
        stage((t + 2) & 31);
        asm volatile("s_waitcnt vmcnt(4)" ::: "memory");
        __builtin_amdgcn_sched_barrier(0);
        __builtin_amdgcn_s_barrier();
        const char* Qs = lds + (t & 3) * 8192;
#pragma unroll
        for (int f = 0; f < 4; f++) {
            bf16x8 qfr[2];
#pragma unroll
            for (int ks = 0; ks < 2; ks++) qfr[ks] = ldswz(Qs, f * 16 + r16, ks, q);
            f32x4 st[2] = {};
#pragma unroll
            for (int jf = 0; jf < 2; jf++)
#pragma unroll
                for (int ks = 0; ks < 2; ks++)
                    st[jf] = __builtin_amdgcn_mfma_f32_16x16x32_bf16(kf[jf][ks], qfr[ks], st[jf], 0, 0, 0);
#pragma unroll
            for (int jf = 0; jf < 2; jf++)
#pragma unroll
                for (int r = 0; r < 4; r++)
                    Zs[jf][r] += exp2fast(st[jf][r] * SCL2);
        }
    }
    asm volatile("s_waitcnt vmcnt(0)" ::: "memory");
#pragma unroll
    for (int jf = 0; jf < 2; jf++)
#pragma unroll
        for (int r = 0; r < 4; r++) {
            float e = Zs[jf][r];
#pragma unroll
            for (int m = 1; m < 16; m <<= 1) e += __shfl_xor(e, m);
            if (r16 == 0)
                L2buf[(size_t)bh * SEQ + j0 + jf * 16 + 4 * q + r] = -log2fast(e);
        }
}

// ---------------- pass 2: X = P @ V, P = 2^(s2 + L2[j]) ----------------
// 4 waves x 32 i share each K/V tile; 2-deep counted-vmcnt, 4 buffers.
__global__ __launch_bounds__(256, 2) void k_attn(const uint16_t* __restrict__ Qm,
                                                 const uint16_t* __restrict__ Km,
                                                 const uint16_t* __restrict__ VT,
                                                 const float* __restrict__ L2,
                                                 uint16_t* __restrict__ Xm) {
    __shared__ char lds[4 * 16384 + 8192];  // 4 x (K 8KB | V 8KB) + L2 table
    char* L2s = lds + 65536;
    const int tid = threadIdx.x, lane = tid & 63, w = tid >> 6;
    const int q = lane >> 4, r16 = lane & 15;
    const int bh = blockIdx.y, b = bh / HEADS, h = bh % HEADS;
    const int iblk = blockIdx.x * 128;
    const uint16_t* Qbase = Qm + (size_t)(b * SEQ + iblk) * DM + h * DK;
    const uint16_t* Kbase = Km + (size_t)b * SEQ * DM + h * DK;
    const uint16_t* VTb = VT + (size_t)bh * DK * SEQ;
    const float* L2b = L2 + (size_t)bh * SEQ;

    // L2 table -> LDS (keeps the hot loop's vmcnt domain pure)
    {
        int o = tid * 32;
        *(float4*)(L2s + o) = *(const float4*)((const char*)L2b + o);
        *(float4*)(L2s + o + 16) = *(const float4*)((const char*)L2b + o + 16);
    }
    // stage block's Q rows [128][128B] swizzled into buf0/1 area, extract qf
#pragma unroll
    for (int c = 0; c < 4; c++) {
        int n = c * 256 + tid, row = n >> 3, u = n & 7;
        gload16(Qbase + (size_t)row * DM + ((u ^ (row & 7)) * 8), lds + n * 16);
    }
    asm volatile("s_waitcnt vmcnt(0)" ::: "memory");
    __syncthreads();
    bf16x8 qf[2][2];
#pragma unroll
    for (int ig = 0; ig < 2; ig++)
#pragma unroll
        for (int ks = 0; ks < 2; ks++)
            qf[ig][ks] = ldswz(lds, w * 32 + ig * 16 + r16, ks, q);
    __syncthreads();

    auto stage = [&](int tt) {
        char* buf = lds + (tt & 3) * 16384;
        int js1 = (tt & 31) * 64;
#pragma unroll
        for (int c = 0; c < 2; c++) {
            int n = c * 256 + tid, row = n >> 3, u = n & 7;
            gload16(Kbase + (size_t)(js1 + row) * DM + ((u ^ (row & 7)) * 8), buf + n * 16);
            gload16(VTb + (size_t)row * SEQ + js1 + ((u ^ (row & 7)) * 8), buf + 8192 + n * 16);
        }
    };
    stage(0); stage(1);
    f32x4 xacc[4][2] = {};  // [dc][ig]
    for (int t = 0; t < 32; ++t) {
        stage((t + 2) & 31);
        asm volatile("s_waitcnt vmcnt(8)" ::: "memory");
        __builtin_amdgcn_sched_barrier(0);
        __builtin_amdgcn_s_barrier();
        const char* Ks = lds + (t & 3) * 16384;
        const char* Vs = Ks + 8192;
        const int js = t * 64;
        bf16x8 kf[4][2], vf[4][2];
#pragma unroll
        for (int jf = 0; jf < 4; jf++)
#pragma unroll
            for (int ks = 0; ks < 2; ks++)
                kf[jf][ks] = ldswz(Ks, jf * 16 + r16, ks, q);
#pragma unroll
        for (int dc = 0; dc < 4; dc++)
#pragma unroll
            for (int c = 0; c < 2; c++)
                vf[dc][c] = ldswz(Vs, dc * 16 + r16, c, q);
        float l2a[4][4];
#pragma unroll
        for (int jf = 0; jf < 4; jf++) {
            float4 lv = *(const float4*)(L2s + (js + jf * 16 + 4 * q) * 4);
            l2a[jf][0] = lv.x; l2a[jf][1] = lv.y; l2a[jf][2] = lv.z; l2a[jf][3] = lv.w;
        }
#pragma unroll
        for (int ig = 0; ig < 2; ig++) {
            f32x4 st[4] = {};
#pragma unroll
            for (int jf = 0; jf < 4; jf++)
#pragma unroll
                for (int ks = 0; ks < 2; ks++)
                    st[jf] = __builtin_amdgcn_mfma_f32_16x16x32_bf16(kf[jf][ks], qf[ig][ks], st[jf], 0, 0, 0);
            bf16x8 pb[2];
#pragma unroll
            for (int c = 0; c < 2; c++) {
                U8 t8;
#pragma unroll
                for (int r = 0; r < 4; r++) {
                    t8.u[r]     = f2bf(exp2fast(st[2 * c][r] * SCL2 + l2a[2 * c][r]));
                    t8.u[4 + r] = f2bf(exp2fast(st[2 * c + 1][r] * SCL2 + l2a[2 * c + 1][r]));
                }
                pb[c] = t8.v;
            }
#pragma unroll
            for (int dc = 0; dc < 4; dc++)
#pragma unroll
                for (int c = 0; c < 2; c++)
                    xacc[dc][ig] = __builtin_amdgcn_mfma_f32_16x16x32_bf16(vf[dc][c], pb[c], xacc[dc][ig], 0, 0, 0);
        }
    }
    asm volatile("s_waitcnt vmcnt(0)" ::: "memory");
    __syncthreads();
    // epilogue: per-wave X^T(d,i) -> X(i,d) via LDS [32 i][144B], coalesced store
    char* xr = lds + w * 4608;
#pragma unroll
    for (int dc = 0; dc < 4; dc++)
#pragma unroll
        for (int ig = 0; ig < 2; ig++) {
            bf16x4 pk;
            pk[0] = (__bf16)xacc[dc][ig][0];
            pk[1] = (__bf16)xacc[dc][ig][1];
            pk[2] = (__bf16)xacc[dc][ig][2];
            pk[3] = (__bf16)xacc[dc][ig][3];
            *(bf16x4*)(xr + (ig * 16 + r16) * 144 + (dc * 16 + 4 * q) * 2) = pk;
        }
    __syncthreads();
#pragma unroll
    for (int cc = 0; cc < 4; cc++) {
        int uidx = cc * 64 + lane;
        int row = uidx >> 3, seg = uidx & 7;
        *(float4*)(Xm + (size_t)(b * SEQ + iblk + w * 32 + row) * DM + h * DK + seg * 8) =
            *(const float4*)(xr + row * 144 + seg * 16);
    }
}

extern "C" void kernel_launch(void* const* d_in, const int* in_sizes, int n_in,
                              void* d_out, int out_size, void* d_ws, size_t ws_size,
                              hipStream_t stream) {
    const float* query = (const float*)d_in[0];
    const float* key = (const float*)d_in[1];
    const float* value = (const float*)d_in[2];
    const float* Wq = (const float*)d_in[3];
    const float* bq = (const float*)d_in[4];
    const float* Wk = (const float*)d_in[5];
    const float* bk = (const float*)d_in[6];
    const float* Wv = (const float*)d_in[7];
    const float* bv = (const float*)d_in[8];
    const float* Wo = (const float*)d_in[9];
    const float* bo = (const float*)d_in[10];
    float* out = (float*)d_out;
    char* ws = (char*)d_ws;

    const size_t SZ = (size_t)ROWS * DM * 2;
    const size_t WSZ = (size_t)DM * DM * 2;
    uint16_t* Qm = (uint16_t*)(ws + 0 * SZ);
    uint16_t* Km = (uint16_t*)(ws + 1 * SZ);
    uint16_t* VT = (uint16_t*)(ws + 2 * SZ);
    uint16_t* Xm = (uint16_t*)(ws + 3 * SZ);
    uint16_t* Wqt = (uint16_t*)(ws + 4 * SZ);
    uint16_t* Wkt = (uint16_t*)(ws + 4 * SZ + WSZ);
    uint16_t* Wvt = (uint16_t*)(ws + 4 * SZ + 2 * WSZ);
    uint16_t* Wot = (uint16_t*)(ws + 4 * SZ + 3 * WSZ);
    float* L2buf = (float*)(ws + 4 * SZ + 4 * WSZ);

    k_transpose<<<dim3(24, 24, 4), 256, 0, stream>>>(Wq, Wk, Wv, Wo, Wqt, Wkt, Wvt, Wot);
    k_gemm_qkv<<<dim3(6, 32, 3), 256, 0, stream>>>(query, key, value, Wqt, bq, bk, bv, Qm, Km, VT);
    k_stats<<<dim3(16, 24), 256, 0, stream>>>(Qm, Km, L2buf);
    k_attn<<<dim3(16, 24), 256, 0, stream>>>(Qm, Km, VT, L2buf, Xm);
    k_gemm_o<<<dim3(6, 32), 256, 0, stream>>>(Xm, Wot, bo, out);
}

// Round 6
// 242.623 us; speedup vs baseline: 1.2205x; 1.0558x over previous
//
#include <hip/hip_runtime.h>
#include <stdint.h>

#define HEADS 12
#define DK 64
#define DM 768
#define BT 2
#define SEQ 2048
#define ROWS (BT*SEQ)

typedef __bf16 bf16x4 __attribute__((ext_vector_type(4)));
typedef __bf16 bf16x8 __attribute__((ext_vector_type(8)));
typedef float f32x4 __attribute__((ext_vector_type(4)));

#define SCL2 0.18033688011112042f  /* (1/8) * log2(e) */

__device__ __forceinline__ float exp2fast(float x) {
#if __has_builtin(__builtin_amdgcn_exp2f)
    return __builtin_amdgcn_exp2f(x);
#else
    return exp2f(x);
#endif
}
__device__ __forceinline__ float rcpfast(float x) {
#if __has_builtin(__builtin_amdgcn_rcpf)
    return __builtin_amdgcn_rcpf(x);
#else
    return 1.0f / x;
#endif
}

__device__ __forceinline__ uint16_t f2bf(float f) {
    union { float f; uint32_t u; } v; v.f = f;
    uint32_t u = v.u;
    return (uint16_t)((u + 0x7FFFu + ((u >> 16) & 1u)) >> 16);
}
__device__ __forceinline__ float bf2f(uint16_t u) {
    union { uint32_t u; float f; } v; v.u = ((uint32_t)u) << 16;
    return v.f;
}

union U8 { uint16_t u[8]; bf16x8 v; float4 f; };

__device__ __forceinline__ bf16x8 cat44(bf16x4 lo, bf16x4 hi) {
    bf16x8 f;
    f[0] = lo[0]; f[1] = lo[1]; f[2] = lo[2]; f[3] = lo[3];
    f[4] = hi[0]; f[5] = hi[1]; f[6] = hi[2]; f[7] = hi[3];
    return f;
}

__device__ __forceinline__ bf16x8 ldfrag(const char* p) {
    bf16x4 lo = *(const bf16x4*)p;
    bf16x4 hi = *(const bf16x4*)(p + 32);
    return cat44(lo, hi);
}

// Fragment read from a [rows][128B] XOR-swizzled LDS tile (16B unit u stored at u^(row&7)).
__device__ __forceinline__ bf16x8 ldswz(const char* base, int row, int ks, int q) {
    int ulo = (ks * 4 + (q >> 1)) ^ (row & 7);
    int uhi = (ks * 4 + 2 + (q >> 1)) ^ (row & 7);
    return cat44(*(const bf16x4*)(base + row * 128 + ulo * 16 + (q & 1) * 8),
                 *(const bf16x4*)(base + row * 128 + uhi * 16 + (q & 1) * 8));
}

// async global->LDS, 16B per lane; LDS dest = wave-uniform base + lane*16.
typedef __attribute__((address_space(3))) void lds_vp;
typedef const __attribute__((address_space(1))) void gbl_vp;
__device__ __forceinline__ void gload16(const void* g, void* l) {
    __builtin_amdgcn_global_load_lds((gbl_vp*)g, (lds_vp*)l, 16, 0, 0);
}

// ---------------- W [k][n] fp32 -> Wt [n][k] bf16 ----------------
__global__ __launch_bounds__(256) void k_transpose(const float* __restrict__ Wq,
                                                   const float* __restrict__ Wk,
                                                   const float* __restrict__ Wv,
                                                   const float* __restrict__ Wo,
                                                   uint16_t* __restrict__ Wqt,
                                                   uint16_t* __restrict__ Wkt,
                                                   uint16_t* __restrict__ Wvt,
                                                   uint16_t* __restrict__ Wot) {
    __shared__ float t[32][33];
    int z = blockIdx.z;
    const float* W = (z == 0) ? Wq : (z == 1) ? Wk : (z == 2) ? Wv : Wo;
    uint16_t* Wt = (z == 0) ? Wqt : (z == 1) ? Wkt : (z == 2) ? Wvt : Wot;
    int bx = blockIdx.x * 32;
    int by = blockIdx.y * 32;
    int tx = threadIdx.x & 31, ty = threadIdx.x >> 5;
#pragma unroll
    for (int r = 0; r < 32; r += 8)
        t[ty + r][tx] = W[(size_t)(bx + ty + r) * DM + by + tx];
    __syncthreads();
#pragma unroll
    for (int r = 0; r < 32; r += 8)
        Wt[(size_t)(by + ty + r) * DM + bx + tx] = f2bf(t[tx][ty + r]);
}

// ---------------- fused QKV GEMM (fp32 A converted in staging) ----------------
__global__ __launch_bounds__(256) void k_gemm_qkv(const float* __restrict__ Aq,
                                                  const float* __restrict__ Ak,
                                                  const float* __restrict__ Av,
                                                  const uint16_t* __restrict__ Wt,
                                                  const float* __restrict__ bq,
                                                  const float* __restrict__ bk,
                                                  const float* __restrict__ bv,
                                                  uint16_t* __restrict__ Qm,
                                                  uint16_t* __restrict__ Km,
                                                  uint16_t* __restrict__ VT) {
    __shared__ char smem[2 * 2 * 128 * 80];
    const int z = blockIdx.z;
    const float* A = (z == 0) ? Aq : (z == 1) ? Ak : Av;
    const uint16_t* Bt = Wt + (size_t)z * DM * DM;
    const float* bias = (z == 0) ? bq : (z == 1) ? bk : bv;
    const int tid = threadIdx.x, lane = tid & 63, w = tid >> 6;
    const int q = lane >> 4, r16 = lane & 15;
    const int mtile = blockIdx.y * 128, ntile = blockIdx.x * 128;
    const int wm = (w >> 1) * 64, wn = (w & 1) * 64;
    const int srow = tid >> 1, shalf = tid & 1;
    const float* ap = A + (size_t)(mtile + srow) * DM + shalf * 16;
    const uint16_t* bp = Bt + (size_t)(ntile + srow) * DM + shalf * 16;
    f32x4 acc[4][4] = {};
    float4 ra0 = *(const float4*)(ap + 0);
    float4 ra1 = *(const float4*)(ap + 4);
    float4 ra2 = *(const float4*)(ap + 8);
    float4 ra3 = *(const float4*)(ap + 12);
    float4 rb0 = *(const float4*)bp;
    float4 rb1 = *(const float4*)((const char*)bp + 16);
    for (int t = 0; t < 24; ++t) {
        char* As = smem + (t & 1) * 20480;
        char* Bs = As + 10240;
        U8 pk0, pk1;
        pk0.u[0] = f2bf(ra0.x); pk0.u[1] = f2bf(ra0.y); pk0.u[2] = f2bf(ra0.z); pk0.u[3] = f2bf(ra0.w);
        pk0.u[4] = f2bf(ra1.x); pk0.u[5] = f2bf(ra1.y); pk0.u[6] = f2bf(ra1.z); pk0.u[7] = f2bf(ra1.w);
        pk1.u[0] = f2bf(ra2.x); pk1.u[1] = f2bf(ra2.y); pk1.u[2] = f2bf(ra2.z); pk1.u[3] = f2bf(ra2.w);
        pk1.u[4] = f2bf(ra3.x); pk1.u[5] = f2bf(ra3.y); pk1.u[6] = f2bf(ra3.z); pk1.u[7] = f2bf(ra3.w);
        *(float4*)(As + srow * 80 + shalf * 32) = pk0.f;
        *(float4*)(As + srow * 80 + shalf * 32 + 16) = pk1.f;
        *(float4*)(Bs + srow * 80 + shalf * 32) = rb0;
        *(float4*)(Bs + srow * 80 + shalf * 32 + 16) = rb1;
        if (t < 23) {
            const float* ap2 = ap + (t + 1) * 32;
            ra0 = *(const float4*)(ap2 + 0);
            ra1 = *(const float4*)(ap2 + 4);
            ra2 = *(const float4*)(ap2 + 8);
            ra3 = *(const float4*)(ap2 + 12);
            const uint16_t* bp2 = bp + (t + 1) * 32;
            rb0 = *(const float4*)bp2;
            rb1 = *(const float4*)((const char*)bp2 + 16);
        }
        __syncthreads();
        bf16x8 af[4], bfr[4];
#pragma unroll
        for (int i = 0; i < 4; i++) {
            af[i] = ldfrag(As + (wm + i * 16 + r16) * 80 + q * 8);
            bfr[i] = ldfrag(Bs + (wn + i * 16 + r16) * 80 + q * 8);
        }
#pragma unroll
        for (int mi = 0; mi < 4; mi++)
#pragma unroll
            for (int ni = 0; ni < 4; ni++)
                acc[mi][ni] = __builtin_amdgcn_mfma_f32_16x16x32_bf16(
                    af[mi], bfr[ni], acc[mi][ni], 0, 0, 0);
    }
    if (z < 2) {
        uint16_t* out = (z == 0) ? Qm : Km;
#pragma unroll
        for (int ni = 0; ni < 4; ni++) {
            int n = ntile + wn + ni * 16 + r16;
            float bv2 = bias[n];
#pragma unroll
            for (int mi = 0; mi < 4; mi++)
#pragma unroll
                for (int r = 0; r < 4; r++) {
                    int m = mtile + wm + mi * 16 + 4 * q + r;
                    out[(size_t)m * DM + n] = f2bf(acc[mi][ni][r] + bv2);
                }
        }
    } else {
#pragma unroll
        for (int ni = 0; ni < 4; ni++) {
            int n = ntile + wn + ni * 16 + r16;
            int h = n >> 6, dk = n & 63;
            float bv2 = bias[n];
#pragma unroll
            for (int mi = 0; mi < 4; mi++) {
                int mbase = mtile + wm + mi * 16 + 4 * q;
                int b = mbase >> 11, s = mbase & 2047;
                ushort4 o;
                o.x = f2bf(acc[mi][ni][0] + bv2);
                o.y = f2bf(acc[mi][ni][1] + bv2);
                o.z = f2bf(acc[mi][ni][2] + bv2);
                o.w = f2bf(acc[mi][ni][3] + bv2);
                *(ushort4*)(VT + ((size_t)((b * HEADS + h) * DK + dk)) * SEQ + s) = o;
            }
        }
    }
}

// ---------------- output GEMM: A = (Xp0 + Xp1) fp32 -> bf16, out fp32 ----------------
__global__ __launch_bounds__(256) void k_gemm_o(const float* __restrict__ Xp0,
                                                const float* __restrict__ Xp1,
                                                const uint16_t* __restrict__ Bt,
                                                const float* __restrict__ bias,
                                                float* __restrict__ C) {
    __shared__ char smem[2 * 2 * 128 * 80];
    const int tid = threadIdx.x, lane = tid & 63, w = tid >> 6;
    const int q = lane >> 4, r16 = lane & 15;
    const int mtile = blockIdx.y * 128, ntile = blockIdx.x * 128;
    const int wm = (w >> 1) * 64, wn = (w & 1) * 64;
    const int srow = tid >> 1, shalf = tid & 1;
    const float* x0 = Xp0 + (size_t)(mtile + srow) * DM + shalf * 16;
    const float* x1 = Xp1 + (size_t)(mtile + srow) * DM + shalf * 16;
    const uint16_t* bp = Bt + (size_t)(ntile + srow) * DM + shalf * 16;
    f32x4 acc[4][4] = {};
    float4 ra0 = *(const float4*)(x0 + 0), ra1 = *(const float4*)(x0 + 4);
    float4 ra2 = *(const float4*)(x0 + 8), ra3 = *(const float4*)(x0 + 12);
    float4 rc0 = *(const float4*)(x1 + 0), rc1 = *(const float4*)(x1 + 4);
    float4 rc2 = *(const float4*)(x1 + 8), rc3 = *(const float4*)(x1 + 12);
    float4 rb0 = *(const float4*)bp;
    float4 rb1 = *(const float4*)((const char*)bp + 16);
    for (int t = 0; t < 24; ++t) {
        char* As = smem + (t & 1) * 20480;
        char* Bs = As + 10240;
        U8 pk0, pk1;
        pk0.u[0] = f2bf(ra0.x + rc0.x); pk0.u[1] = f2bf(ra0.y + rc0.y);
        pk0.u[2] = f2bf(ra0.z + rc0.z); pk0.u[3] = f2bf(ra0.w + rc0.w);
        pk0.u[4] = f2bf(ra1.x + rc1.x); pk0.u[5] = f2bf(ra1.y + rc1.y);
        pk0.u[6] = f2bf(ra1.z + rc1.z); pk0.u[7] = f2bf(ra1.w + rc1.w);
        pk1.u[0] = f2bf(ra2.x + rc2.x); pk1.u[1] = f2bf(ra2.y + rc2.y);
        pk1.u[2] = f2bf(ra2.z + rc2.z); pk1.u[3] = f2bf(ra2.w + rc2.w);
        pk1.u[4] = f2bf(ra3.x + rc3.x); pk1.u[5] = f2bf(ra3.y + rc3.y);
        pk1.u[6] = f2bf(ra3.z + rc3.z); pk1.u[7] = f2bf(ra3.w + rc3.w);
        *(float4*)(As + srow * 80 + shalf * 32) = pk0.f;
        *(float4*)(As + srow * 80 + shalf * 32 + 16) = pk1.f;
        *(float4*)(Bs + srow * 80 + shalf * 32) = rb0;
        *(float4*)(Bs + srow * 80 + shalf * 32 + 16) = rb1;
        if (t < 23) {
            const float* x0n = x0 + (t + 1) * 32;
            const float* x1n = x1 + (t + 1) * 32;
            ra0 = *(const float4*)(x0n + 0); ra1 = *(const float4*)(x0n + 4);
            ra2 = *(const float4*)(x0n + 8); ra3 = *(const float4*)(x0n + 12);
            rc0 = *(const float4*)(x1n + 0); rc1 = *(const float4*)(x1n + 4);
            rc2 = *(const float4*)(x1n + 8); rc3 = *(const float4*)(x1n + 12);
            const uint16_t* bp2 = bp + (t + 1) * 32;
            rb0 = *(const float4*)bp2;
            rb1 = *(const float4*)((const char*)bp2 + 16);
        }
        __syncthreads();
        bf16x8 af[4], bfr[4];
#pragma unroll
        for (int i = 0; i < 4; i++) {
            af[i] = ldfrag(As + (wm + i * 16 + r16) * 80 + q * 8);
            bfr[i] = ldfrag(Bs + (wn + i * 16 + r16) * 80 + q * 8);
        }
#pragma unroll
        for (int mi = 0; mi < 4; mi++)
#pragma unroll
            for (int ni = 0; ni < 4; ni++)
                acc[mi][ni] = __builtin_amdgcn_mfma_f32_16x16x32_bf16(
                    af[mi], bfr[ni], acc[mi][ni], 0, 0, 0);
    }
#pragma unroll
    for (int ni = 0; ni < 4; ni++) {
        int n = ntile + wn + ni * 16 + r16;
        float bv = bias[n];
#pragma unroll
        for (int mi = 0; mi < 4; mi++)
#pragma unroll
            for (int r = 0; r < 4; r++) {
                int m = mtile + wm + mi * 16 + 4 * q + r;
                C[(size_t)m * DM + n] = acc[mi][ni][r] + bv;
            }
    }
}

// ---------------- pass 1: Zpart[ihalf][bh][j] = sum_{i in half} 2^(s2[i][j]) ----------------
// 4 waves x 32 j; K frags in regs; Q streamed, 3 buffers, 1-deep prefetch, vmcnt(2).
__global__ __launch_bounds__(256, 3) void k_stats(const uint16_t* __restrict__ Qm,
                                                  const uint16_t* __restrict__ Km,
                                                  float* __restrict__ Zpart) {
    __shared__ char lds[3 * 8192];
    const int tid = threadIdx.x, lane = tid & 63, w = tid >> 6;
    const int q = lane >> 4, r16 = lane & 15;
    const int bh = blockIdx.y, b = bh / HEADS, h = bh % HEADS;
    const int j0 = blockIdx.x * 128 + w * 32;
    const int ihalf = blockIdx.z;
    const uint16_t* Qbase = Qm + (size_t)(b * SEQ + ihalf * 1024) * DM + h * DK;
    const uint16_t* Kbase = Km + (size_t)(b * SEQ + blockIdx.x * 128) * DM + h * DK;

    // prologue: stage this block's K rows [128][128B] swizzled, extract kf
#pragma unroll
    for (int c = 0; c < 4; c++) {
        int n = c * 256 + tid, row = n >> 3, u = n & 7;
        gload16(Kbase + (size_t)row * DM + ((u ^ (row & 7)) * 8), lds + n * 16);
    }
    asm volatile("s_waitcnt vmcnt(0)" ::: "memory");
    __syncthreads();
    bf16x8 kf[2][2];
#pragma unroll
    for (int jf = 0; jf < 2; jf++)
#pragma unroll
        for (int ks = 0; ks < 2; ks++)
            kf[jf][ks] = ldswz(lds, w * 32 + jf * 16 + r16, ks, q);
    __syncthreads();

    auto stageQ = [&](char* buf, int tt) {
        int i1 = (tt & 15) * 64;
#pragma unroll
        for (int c = 0; c < 2; c++) {
            int n = c * 256 + tid, row = n >> 3, u = n & 7;
            gload16(Qbase + (size_t)(i1 + row) * DM + ((u ^ (row & 7)) * 8), buf + n * 16);
        }
    };
    char* p0 = lds;
    char* p1 = lds + 8192;
    char* p2 = lds + 16384;
    stageQ(p0, 0);
    float Zs[2][4] = {};
    for (int t = 0; t < 16; ++t) {
        stageQ(p1, t + 1);
        asm volatile("s_waitcnt vmcnt(2)" ::: "memory");
        __builtin_amdgcn_sched_barrier(0);
        __builtin_amdgcn_s_barrier();
        __builtin_amdgcn_s_setprio(1);
#pragma unroll
        for (int f = 0; f < 4; f++) {
            bf16x8 qfr[2];
#pragma unroll
            for (int ks = 0; ks < 2; ks++) qfr[ks] = ldswz(p0, f * 16 + r16, ks, q);
            f32x4 st[2] = {};
#pragma unroll
            for (int jf = 0; jf < 2; jf++)
#pragma unroll
                for (int ks = 0; ks < 2; ks++)
                    st[jf] = __builtin_amdgcn_mfma_f32_16x16x32_bf16(kf[jf][ks], qfr[ks], st[jf], 0, 0, 0);
#pragma unroll
            for (int jf = 0; jf < 2; jf++)
#pragma unroll
                for (int r = 0; r < 4; r++)
                    Zs[jf][r] += exp2fast(st[jf][r] * SCL2);
        }
        __builtin_amdgcn_s_setprio(0);
        char* tp = p0; p0 = p1; p1 = p2; p2 = tp;
    }
    asm volatile("s_waitcnt vmcnt(0)" ::: "memory");
#pragma unroll
    for (int jf = 0; jf < 2; jf++)
#pragma unroll
        for (int r = 0; r < 4; r++) {
            float e = Zs[jf][r];
#pragma unroll
            for (int m = 1; m < 16; m <<= 1) e += __shfl_xor(e, m);
            if (r16 == 0)
                Zpart[((size_t)ihalf * 24 + bh) * SEQ + j0 + jf * 16 + 4 * q + r] = e;
        }
}

// ---------------- scale V^T rows by 1/(Zp0[j]+Zp1[j]) in place ----------------
__global__ __launch_bounds__(256) void k_vscale(uint16_t* __restrict__ VT,
                                                const float* __restrict__ Zpart) {
    size_t t = (size_t)blockIdx.x * 256 + threadIdx.x;
    size_t base = t * 8;
    int rowid = (int)(base >> 11);
    int bh = rowid >> 6;
    int s0 = (int)(base & 2047);
    const float* z0p = Zpart + (size_t)bh * SEQ + s0;
    const float* z1p = Zpart + (size_t)24 * SEQ + (size_t)bh * SEQ + s0;
    float4 a0 = *(const float4*)z0p, a1 = *(const float4*)(z0p + 4);
    float4 b0 = *(const float4*)z1p, b1 = *(const float4*)(z1p + 4);
    ushort4 va = *(ushort4*)(VT + base);
    ushort4 vb = *(ushort4*)(VT + base + 4);
    ushort4 oa, oc;
    oa.x = f2bf(bf2f(va.x) * rcpfast(a0.x + b0.x));
    oa.y = f2bf(bf2f(va.y) * rcpfast(a0.y + b0.y));
    oa.z = f2bf(bf2f(va.z) * rcpfast(a0.z + b0.z));
    oa.w = f2bf(bf2f(va.w) * rcpfast(a0.w + b0.w));
    oc.x = f2bf(bf2f(vb.x) * rcpfast(a1.x + b1.x));
    oc.y = f2bf(bf2f(vb.y) * rcpfast(a1.y + b1.y));
    oc.z = f2bf(bf2f(vb.z) * rcpfast(a1.z + b1.z));
    oc.w = f2bf(bf2f(vb.w) * rcpfast(a1.w + b1.w));
    *(ushort4*)(VT + base) = oa;
    *(ushort4*)(VT + base + 4) = oc;
}

// ---------------- pass 2: Xp[jhalf] = sum_{j in half} 2^(s2) * V'[j] ----------------
// 4 waves x 32 i; 3 buffers x (K 8KB | V 8KB), 1-deep prefetch, vmcnt(4); fp32 out.
__global__ __launch_bounds__(256, 3) void k_attn(const uint16_t* __restrict__ Qm,
                                                 const uint16_t* __restrict__ Km,
                                                 const uint16_t* __restrict__ VT,
                                                 float* __restrict__ Xp) {
    __shared__ char lds[3 * 16384];
    const int tid = threadIdx.x, lane = tid & 63, w = tid >> 6;
    const int q = lane >> 4, r16 = lane & 15;
    const int bh = blockIdx.y, b = bh / HEADS, h = bh % HEADS;
    const int iblk = blockIdx.x * 128;
    const int jbase = blockIdx.z * 1024;
    const uint16_t* Qbase = Qm + (size_t)(b * SEQ + iblk) * DM + h * DK;
    const uint16_t* Kbase = Km + (size_t)(b * SEQ + jbase) * DM + h * DK;
    const uint16_t* VTb = VT + (size_t)bh * DK * SEQ + jbase;
    float* Xout = Xp + (size_t)blockIdx.z * ROWS * DM;

    // prologue: stage this block's Q rows [128][128B] swizzled, extract qf
#pragma unroll
    for (int c = 0; c < 4; c++) {
        int n = c * 256 + tid, row = n >> 3, u = n & 7;
        gload16(Qbase + (size_t)row * DM + ((u ^ (row & 7)) * 8), lds + n * 16);
    }
    asm volatile("s_waitcnt vmcnt(0)" ::: "memory");
    __syncthreads();
    bf16x8 qf[2][2];
#pragma unroll
    for (int ig = 0; ig < 2; ig++)
#pragma unroll
        for (int ks = 0; ks < 2; ks++)
            qf[ig][ks] = ldswz(lds, w * 32 + ig * 16 + r16, ks, q);
    __syncthreads();

    auto stageKV = [&](char* buf, int tt) {
        int js1 = (tt & 15) * 64;
#pragma unroll
        for (int c = 0; c < 2; c++) {
            int n = c * 256 + tid, row = n >> 3, u = n & 7;
            gload16(Kbase + (size_t)(js1 + row) * DM + ((u ^ (row & 7)) * 8), buf + n * 16);
            gload16(VTb + (size_t)row * SEQ + js1 + ((u ^ (row & 7)) * 8), buf + 8192 + n * 16);
        }
    };
    char* p0 = lds;
    char* p1 = lds + 16384;
    char* p2 = lds + 32768;
    stageKV(p0, 0);
    f32x4 xacc[4][2] = {};  // [dc][ig]
    for (int t = 0; t < 16; ++t) {
        stageKV(p1, t + 1);
        asm volatile("s_waitcnt vmcnt(4)" ::: "memory");
        __builtin_amdgcn_sched_barrier(0);
        __builtin_amdgcn_s_barrier();
        __builtin_amdgcn_s_setprio(1);
        const char* Ks = p0;
        const char* Vs = p0 + 8192;
        bf16x8 kf[4][2], vf[4][2];
#pragma unroll
        for (int jf = 0; jf < 4; jf++)
#pragma unroll
            for (int ks = 0; ks < 2; ks++)
                kf[jf][ks] = ldswz(Ks, jf * 16 + r16, ks, q);
#pragma unroll
        for (int dc = 0; dc < 4; dc++)
#pragma unroll
            for (int c = 0; c < 2; c++)
                vf[dc][c] = ldswz(Vs, dc * 16 + r16, c, q);
#pragma unroll
        for (int ig = 0; ig < 2; ig++) {
            f32x4 st[4] = {};
#pragma unroll
            for (int jf = 0; jf < 4; jf++)
#pragma unroll
                for (int ks = 0; ks < 2; ks++)
                    st[jf] = __builtin_amdgcn_mfma_f32_16x16x32_bf16(kf[jf][ks], qf[ig][ks], st[jf], 0, 0, 0);
            bf16x8 pb[2];
#pragma unroll
            for (int c = 0; c < 2; c++) {
                U8 t8;
#pragma unroll
                for (int r = 0; r < 4; r++) {
                    t8.u[r]     = f2bf(exp2fast(st[2 * c][r] * SCL2));
                    t8.u[4 + r] = f2bf(exp2fast(st[2 * c + 1][r] * SCL2));
                }
                pb[c] = t8.v;
            }
#pragma unroll
            for (int dc = 0; dc < 4; dc++)
#pragma unroll
                for (int c = 0; c < 2; c++)
                    xacc[dc][ig] = __builtin_amdgcn_mfma_f32_16x16x32_bf16(vf[dc][c], pb[c], xacc[dc][ig], 0, 0, 0);
        }
        __builtin_amdgcn_s_setprio(0);
        char* tp = p0; p0 = p1; p1 = p2; p2 = tp;
    }
    asm volatile("s_waitcnt vmcnt(0)" ::: "memory");
    __syncthreads();
    // epilogue: per-wave fp32 X^T(d,i) -> X(i,d) via LDS [32 i][264B], then store
    char* xr = lds + w * 8448;
#pragma unroll
    for (int dc = 0; dc < 4; dc++)
#pragma unroll
        for (int ig = 0; ig < 2; ig++)
            *(f32x4*)(xr + (ig * 16 + r16) * 264 + (dc * 16 + 4 * q) * 4) = xacc[dc][ig];
    __syncthreads();
#pragma unroll
    for (int cc = 0; cc < 8; cc++) {
        int uidx = cc * 64 + lane;
        int row = uidx >> 4, seg = uidx & 15;
        *(float4*)(Xout + (size_t)(b * SEQ + iblk + w * 32 + row) * DM + h * DK + seg * 4) =
            *(const float4*)(xr + row * 264 + seg * 16);
    }
}

extern "C" void kernel_launch(void* const* d_in, const int* in_sizes, int n_in,
                              void* d_out, int out_size, void* d_ws, size_t ws_size,
                              hipStream_t stream) {
    const float* query = (const float*)d_in[0];
    const float* key = (const float*)d_in[1];
    const float* value = (const float*)d_in[2];
    const float* Wq = (const float*)d_in[3];
    const float* bq = (const float*)d_in[4];
    const float* Wk = (const float*)d_in[5];
    const float* bk = (const float*)d_in[6];
    const float* Wv = (const float*)d_in[7];
    const float* bv = (const float*)d_in[8];
    const float* Wo = (const float*)d_in[9];
    const float* bo = (const float*)d_in[10];
    float* out = (float*)d_out;
    char* ws = (char*)d_ws;

    const size_t SZ = (size_t)ROWS * DM * 2;         // 6.29 MB bf16 tensor
    const size_t WSZ = (size_t)DM * DM * 2;          // 1.18 MB bf16 weight
    const size_t XSZ = (size_t)ROWS * DM * 4;        // 12.58 MB fp32 partial
    uint16_t* Qm = (uint16_t*)(ws + 0 * SZ);
    uint16_t* Km = (uint16_t*)(ws + 1 * SZ);
    uint16_t* VT = (uint16_t*)(ws + 2 * SZ);
    uint16_t* Wqt = (uint16_t*)(ws + 3 * SZ);
    uint16_t* Wkt = (uint16_t*)(ws + 3 * SZ + WSZ);
    uint16_t* Wvt = (uint16_t*)(ws + 3 * SZ + 2 * WSZ);
    uint16_t* Wot = (uint16_t*)(ws + 3 * SZ + 3 * WSZ);
    float* Zpart = (float*)(ws + 3 * SZ + 4 * WSZ);  // [2][24][2048] f32
    char* xbase = ws + 3 * SZ + 4 * WSZ + 2 * 24 * SEQ * 4;
    float* Xp0 = (float*)xbase;
    float* Xp1 = (float*)(xbase + XSZ);

    k_transpose<<<dim3(24, 24, 4), 256, 0, stream>>>(Wq, Wk, Wv, Wo, Wqt, Wkt, Wvt, Wot);
    k_gemm_qkv<<<dim3(6, 32, 3), 256, 0, stream>>>(query, key, value, Wqt, bq, bk, bv, Qm, Km, VT);
    k_stats<<<dim3(16, 24, 2), 256, 0, stream>>>(Qm, Km, Zpart);
    k_vscale<<<dim3(1536), 256, 0, stream>>>(VT, Zpart);
    k_attn<<<dim3(16, 24, 2), 256, 0, stream>>>(Qm, Km, VT, Xp0);
    k_gemm_o<<<dim3(6, 32), 256, 0, stream>>>(Xp0, Xp1, Wot, bo, out);
}

// Round 7
// 239.666 us; speedup vs baseline: 1.2355x; 1.0123x over previous
//
#include <hip/hip_runtime.h>
#include <stdint.h>

#define HEADS 12
#define DK 64
#define DM 768
#define BT 2
#define SEQ 2048
#define ROWS (BT*SEQ)

typedef __bf16 bf16x4 __attribute__((ext_vector_type(4)));
typedef __bf16 bf16x8 __attribute__((ext_vector_type(8)));
typedef float f32x4 __attribute__((ext_vector_type(4)));

#define SCL2 0.18033688011112042f  /* (1/8) * log2(e) */

__device__ __forceinline__ float exp2fast(float x) {
#if __has_builtin(__builtin_amdgcn_exp2f)
    return __builtin_amdgcn_exp2f(x);
#else
    return exp2f(x);
#endif
}
__device__ __forceinline__ float rcpfast(float x) {
#if __has_builtin(__builtin_amdgcn_rcpf)
    return __builtin_amdgcn_rcpf(x);
#else
    return 1.0f / x;
#endif
}

__device__ __forceinline__ uint16_t f2bf(float f) {
    union { float f; uint32_t u; } v; v.f = f;
    uint32_t u = v.u;
    return (uint16_t)((u + 0x7FFFu + ((u >> 16) & 1u)) >> 16);
}
__device__ __forceinline__ float bf2f(uint16_t u) {
    union { uint32_t u; float f; } v; v.u = ((uint32_t)u) << 16;
    return v.f;
}

// XCD-aware bijective remap: grid size must be divisible by 8.
__device__ __forceinline__ int xcdswz(int bid, int per_xcd) {
    return (bid & 7) * per_xcd + (bid >> 3);
}

union U8 { uint16_t u[8]; bf16x8 v; float4 f; };

__device__ __forceinline__ bf16x8 cat44(bf16x4 lo, bf16x4 hi) {
    bf16x8 f;
    f[0] = lo[0]; f[1] = lo[1]; f[2] = lo[2]; f[3] = lo[3];
    f[4] = hi[0]; f[5] = hi[1]; f[6] = hi[2]; f[7] = hi[3];
    return f;
}

__device__ __forceinline__ bf16x8 ldfrag(const char* p) {
    bf16x4 lo = *(const bf16x4*)p;
    bf16x4 hi = *(const bf16x4*)(p + 32);
    return cat44(lo, hi);
}

// Fragment read from a [rows][128B] XOR-swizzled LDS tile (16B unit u stored at u^(row&7)).
__device__ __forceinline__ bf16x8 ldswz(const char* base, int row, int ks, int q) {
    int ulo = (ks * 4 + (q >> 1)) ^ (row & 7);
    int uhi = (ks * 4 + 2 + (q >> 1)) ^ (row & 7);
    return cat44(*(const bf16x4*)(base + row * 128 + ulo * 16 + (q & 1) * 8),
                 *(const bf16x4*)(base + row * 128 + uhi * 16 + (q & 1) * 8));
}

// async global->LDS, 16B per lane; LDS dest = wave-uniform base + lane*16.
typedef __attribute__((address_space(3))) void lds_vp;
typedef const __attribute__((address_space(1))) void gbl_vp;
__device__ __forceinline__ void gload16(const void* g, void* l) {
    __builtin_amdgcn_global_load_lds((gbl_vp*)g, (lds_vp*)l, 16, 0, 0);
}

// ---------------- W [k][n] fp32 -> Wt [n][k] bf16 ----------------
__global__ __launch_bounds__(256) void k_transpose(const float* __restrict__ Wq,
                                                   const float* __restrict__ Wk,
                                                   const float* __restrict__ Wv,
                                                   const float* __restrict__ Wo,
                                                   uint16_t* __restrict__ Wqt,
                                                   uint16_t* __restrict__ Wkt,
                                                   uint16_t* __restrict__ Wvt,
                                                   uint16_t* __restrict__ Wot) {
    __shared__ float t[32][33];
    int z = blockIdx.z;
    const float* W = (z == 0) ? Wq : (z == 1) ? Wk : (z == 2) ? Wv : Wo;
    uint16_t* Wt = (z == 0) ? Wqt : (z == 1) ? Wkt : (z == 2) ? Wvt : Wot;
    int bx = blockIdx.x * 32;
    int by = blockIdx.y * 32;
    int tx = threadIdx.x & 31, ty = threadIdx.x >> 5;
#pragma unroll
    for (int r = 0; r < 32; r += 8)
        t[ty + r][tx] = W[(size_t)(bx + ty + r) * DM + by + tx];
    __syncthreads();
#pragma unroll
    for (int r = 0; r < 32; r += 8)
        Wt[(size_t)(by + ty + r) * DM + bx + tx] = f2bf(t[tx][ty + r]);
}

// ---------------- fused QKV GEMM (fp32 A converted in staging) ----------------
// 1D grid 576, XCD-swizzled, rid -> (z, mtile, ntile) with n fastest.
__global__ __launch_bounds__(256) void k_gemm_qkv(const float* __restrict__ Aq,
                                                  const float* __restrict__ Ak,
                                                  const float* __restrict__ Av,
                                                  const uint16_t* __restrict__ Wt,
                                                  const float* __restrict__ bq,
                                                  const float* __restrict__ bk,
                                                  const float* __restrict__ bv,
                                                  uint16_t* __restrict__ Qm,
                                                  uint16_t* __restrict__ Km,
                                                  uint16_t* __restrict__ VT) {
    __shared__ char smem[2 * 2 * 128 * 80];
    const int rid = xcdswz(blockIdx.x, 72);
    const int z = rid / 192;
    const int rem = rid % 192;
    const float* A = (z == 0) ? Aq : (z == 1) ? Ak : Av;
    const uint16_t* Bt = Wt + (size_t)z * DM * DM;
    const float* bias = (z == 0) ? bq : (z == 1) ? bk : bv;
    const int tid = threadIdx.x, lane = tid & 63, w = tid >> 6;
    const int q = lane >> 4, r16 = lane & 15;
    const int mtile = (rem / 6) * 128, ntile = (rem % 6) * 128;
    const int wm = (w >> 1) * 64, wn = (w & 1) * 64;
    const int srow = tid >> 1, shalf = tid & 1;
    const float* ap = A + (size_t)(mtile + srow) * DM + shalf * 16;
    const uint16_t* bp = Bt + (size_t)(ntile + srow) * DM + shalf * 16;
    f32x4 acc[4][4] = {};
    float4 ra0 = *(const float4*)(ap + 0);
    float4 ra1 = *(const float4*)(ap + 4);
    float4 ra2 = *(const float4*)(ap + 8);
    float4 ra3 = *(const float4*)(ap + 12);
    float4 rb0 = *(const float4*)bp;
    float4 rb1 = *(const float4*)((const char*)bp + 16);
    for (int t = 0; t < 24; ++t) {
        char* As = smem + (t & 1) * 20480;
        char* Bs = As + 10240;
        U8 pk0, pk1;
        pk0.u[0] = f2bf(ra0.x); pk0.u[1] = f2bf(ra0.y); pk0.u[2] = f2bf(ra0.z); pk0.u[3] = f2bf(ra0.w);
        pk0.u[4] = f2bf(ra1.x); pk0.u[5] = f2bf(ra1.y); pk0.u[6] = f2bf(ra1.z); pk0.u[7] = f2bf(ra1.w);
        pk1.u[0] = f2bf(ra2.x); pk1.u[1] = f2bf(ra2.y); pk1.u[2] = f2bf(ra2.z); pk1.u[3] = f2bf(ra2.w);
        pk1.u[4] = f2bf(ra3.x); pk1.u[5] = f2bf(ra3.y); pk1.u[6] = f2bf(ra3.z); pk1.u[7] = f2bf(ra3.w);
        *(float4*)(As + srow * 80 + shalf * 32) = pk0.f;
        *(float4*)(As + srow * 80 + shalf * 32 + 16) = pk1.f;
        *(float4*)(Bs + srow * 80 + shalf * 32) = rb0;
        *(float4*)(Bs + srow * 80 + shalf * 32 + 16) = rb1;
        if (t < 23) {
            const float* ap2 = ap + (t + 1) * 32;
            ra0 = *(const float4*)(ap2 + 0);
            ra1 = *(const float4*)(ap2 + 4);
            ra2 = *(const float4*)(ap2 + 8);
            ra3 = *(const float4*)(ap2 + 12);
            const uint16_t* bp2 = bp + (t + 1) * 32;
            rb0 = *(const float4*)bp2;
            rb1 = *(const float4*)((const char*)bp2 + 16);
        }
        __syncthreads();
        bf16x8 af[4], bfr[4];
#pragma unroll
        for (int i = 0; i < 4; i++) {
            af[i] = ldfrag(As + (wm + i * 16 + r16) * 80 + q * 8);
            bfr[i] = ldfrag(Bs + (wn + i * 16 + r16) * 80 + q * 8);
        }
#pragma unroll
        for (int mi = 0; mi < 4; mi++)
#pragma unroll
            for (int ni = 0; ni < 4; ni++)
                acc[mi][ni] = __builtin_amdgcn_mfma_f32_16x16x32_bf16(
                    af[mi], bfr[ni], acc[mi][ni], 0, 0, 0);
    }
    if (z < 2) {
        uint16_t* out = (z == 0) ? Qm : Km;
#pragma unroll
        for (int ni = 0; ni < 4; ni++) {
            int n = ntile + wn + ni * 16 + r16;
            float bv2 = bias[n];
#pragma unroll
            for (int mi = 0; mi < 4; mi++)
#pragma unroll
                for (int r = 0; r < 4; r++) {
                    int m = mtile + wm + mi * 16 + 4 * q + r;
                    out[(size_t)m * DM + n] = f2bf(acc[mi][ni][r] + bv2);
                }
        }
    } else {
#pragma unroll
        for (int ni = 0; ni < 4; ni++) {
            int n = ntile + wn + ni * 16 + r16;
            int h = n >> 6, dk = n & 63;
            float bv2 = bias[n];
#pragma unroll
            for (int mi = 0; mi < 4; mi++) {
                int mbase = mtile + wm + mi * 16 + 4 * q;
                int b = mbase >> 11, s = mbase & 2047;
                ushort4 o;
                o.x = f2bf(acc[mi][ni][0] + bv2);
                o.y = f2bf(acc[mi][ni][1] + bv2);
                o.z = f2bf(acc[mi][ni][2] + bv2);
                o.w = f2bf(acc[mi][ni][3] + bv2);
                *(ushort4*)(VT + ((size_t)((b * HEADS + h) * DK + dk)) * SEQ + s) = o;
            }
        }
    }
}

// ---------------- output GEMM: A = (Xp0 + Xp1) fp32 -> bf16, out fp32 ----------------
// 1D grid 192, XCD-swizzled, rid -> (mtile, ntile) n-fastest.
__global__ __launch_bounds__(256) void k_gemm_o(const float* __restrict__ Xp0,
                                                const float* __restrict__ Xp1,
                                                const uint16_t* __restrict__ Bt,
                                                const float* __restrict__ bias,
                                                float* __restrict__ C) {
    __shared__ char smem[2 * 2 * 128 * 80];
    const int rid = xcdswz(blockIdx.x, 24);
    const int tid = threadIdx.x, lane = tid & 63, w = tid >> 6;
    const int q = lane >> 4, r16 = lane & 15;
    const int mtile = (rid / 6) * 128, ntile = (rid % 6) * 128;
    const int wm = (w >> 1) * 64, wn = (w & 1) * 64;
    const int srow = tid >> 1, shalf = tid & 1;
    const float* x0 = Xp0 + (size_t)(mtile + srow) * DM + shalf * 16;
    const float* x1 = Xp1 + (size_t)(mtile + srow) * DM + shalf * 16;
    const uint16_t* bp = Bt + (size_t)(ntile + srow) * DM + shalf * 16;
    f32x4 acc[4][4] = {};
    float4 ra0 = *(const float4*)(x0 + 0), ra1 = *(const float4*)(x0 + 4);
    float4 ra2 = *(const float4*)(x0 + 8), ra3 = *(const float4*)(x0 + 12);
    float4 rc0 = *(const float4*)(x1 + 0), rc1 = *(const float4*)(x1 + 4);
    float4 rc2 = *(const float4*)(x1 + 8), rc3 = *(const float4*)(x1 + 12);
    float4 rb0 = *(const float4*)bp;
    float4 rb1 = *(const float4*)((const char*)bp + 16);
    for (int t = 0; t < 24; ++t) {
        char* As = smem + (t & 1) * 20480;
        char* Bs = As + 10240;
        U8 pk0, pk1;
        pk0.u[0] = f2bf(ra0.x + rc0.x); pk0.u[1] = f2bf(ra0.y + rc0.y);
        pk0.u[2] = f2bf(ra0.z + rc0.z); pk0.u[3] = f2bf(ra0.w + rc0.w);
        pk0.u[4] = f2bf(ra1.x + rc1.x); pk0.u[5] = f2bf(ra1.y + rc1.y);
        pk0.u[6] = f2bf(ra1.z + rc1.z); pk0.u[7] = f2bf(ra1.w + rc1.w);
        pk1.u[0] = f2bf(ra2.x + rc2.x); pk1.u[1] = f2bf(ra2.y + rc2.y);
        pk1.u[2] = f2bf(ra2.z + rc2.z); pk1.u[3] = f2bf(ra2.w + rc2.w);
        pk1.u[4] = f2bf(ra3.x + rc3.x); pk1.u[5] = f2bf(ra3.y + rc3.y);
        pk1.u[6] = f2bf(ra3.z + rc3.z); pk1.u[7] = f2bf(ra3.w + rc3.w);
        *(float4*)(As + srow * 80 + shalf * 32) = pk0.f;
        *(float4*)(As + srow * 80 + shalf * 32 + 16) = pk1.f;
        *(float4*)(Bs + srow * 80 + shalf * 32) = rb0;
        *(float4*)(Bs + srow * 80 + shalf * 32 + 16) = rb1;
        if (t < 23) {
            const float* x0n = x0 + (t + 1) * 32;
            const float* x1n = x1 + (t + 1) * 32;
            ra0 = *(const float4*)(x0n + 0); ra1 = *(const float4*)(x0n + 4);
            ra2 = *(const float4*)(x0n + 8); ra3 = *(const float4*)(x0n + 12);
            rc0 = *(const float4*)(x1n + 0); rc1 = *(const float4*)(x1n + 4);
            rc2 = *(const float4*)(x1n + 8); rc3 = *(const float4*)(x1n + 12);
            const uint16_t* bp2 = bp + (t + 1) * 32;
            rb0 = *(const float4*)bp2;
            rb1 = *(const float4*)((const char*)bp2 + 16);
        }
        __syncthreads();
        bf16x8 af[4], bfr[4];
#pragma unroll
        for (int i = 0; i < 4; i++) {
            af[i] = ldfrag(As + (wm + i * 16 + r16) * 80 + q * 8);
            bfr[i] = ldfrag(Bs + (wn + i * 16 + r16) * 80 + q * 8);
        }
#pragma unroll
        for (int mi = 0; mi < 4; mi++)
#pragma unroll
            for (int ni = 0; ni < 4; ni++)
                acc[mi][ni] = __builtin_amdgcn_mfma_f32_16x16x32_bf16(
                    af[mi], bfr[ni], acc[mi][ni], 0, 0, 0);
    }
#pragma unroll
    for (int ni = 0; ni < 4; ni++) {
        int n = ntile + wn + ni * 16 + r16;
        float bv = bias[n];
#pragma unroll
        for (int mi = 0; mi < 4; mi++)
#pragma unroll
            for (int r = 0; r < 4; r++) {
                int m = mtile + wm + mi * 16 + 4 * q + r;
                C[(size_t)m * DM + n] = acc[mi][ni][r] + bv;
            }
    }
}

// ---------------- pass 1: Zpart[ihalf][bh][j] = sum_{i in half} 2^(s2[i][j]) ----------------
// 1D grid 768, XCD-swizzled, rid -> (bh, jtile, ihalf); 4 waves x 32 j.
__global__ __launch_bounds__(256, 3) void k_stats(const uint16_t* __restrict__ Qm,
                                                  const uint16_t* __restrict__ Km,
                                                  float* __restrict__ Zpart) {
    __shared__ char lds[3 * 8192];
    const int rid = xcdswz(blockIdx.x, 96);
    const int bh = rid / 32, rem = rid % 32;
    const int jtile = rem >> 1, ihalf = rem & 1;
    const int tid = threadIdx.x, lane = tid & 63, w = tid >> 6;
    const int q = lane >> 4, r16 = lane & 15;
    const int b = bh / HEADS, h = bh % HEADS;
    const int j0 = jtile * 128 + w * 32;
    const uint16_t* Qbase = Qm + (size_t)(b * SEQ + ihalf * 1024) * DM + h * DK;
    const uint16_t* Kbase = Km + (size_t)(b * SEQ + jtile * 128) * DM + h * DK;

    // prologue: stage this block's K rows [128][128B] swizzled, extract kf
#pragma unroll
    for (int c = 0; c < 4; c++) {
        int n = c * 256 + tid, row = n >> 3, u = n & 7;
        gload16(Kbase + (size_t)row * DM + ((u ^ (row & 7)) * 8), lds + n * 16);
    }
    asm volatile("s_waitcnt vmcnt(0)" ::: "memory");
    __syncthreads();
    bf16x8 kf[2][2];
#pragma unroll
    for (int jf = 0; jf < 2; jf++)
#pragma unroll
        for (int ks = 0; ks < 2; ks++)
            kf[jf][ks] = ldswz(lds, w * 32 + jf * 16 + r16, ks, q);
    __syncthreads();

    auto stageQ = [&](char* buf, int tt) {
        int i1 = (tt & 15) * 64;
#pragma unroll
        for (int c = 0; c < 2; c++) {
            int n = c * 256 + tid, row = n >> 3, u = n & 7;
            gload16(Qbase + (size_t)(i1 + row) * DM + ((u ^ (row & 7)) * 8), buf + n * 16);
        }
    };
    char* p0 = lds;
    char* p1 = lds + 8192;
    char* p2 = lds + 16384;
    stageQ(p0, 0);
    float Zs[2][4] = {};
    for (int t = 0; t < 16; ++t) {
        stageQ(p1, t + 1);
        asm volatile("s_waitcnt vmcnt(2)" ::: "memory");
        __builtin_amdgcn_sched_barrier(0);
        __builtin_amdgcn_s_barrier();
        __builtin_amdgcn_s_setprio(1);
#pragma unroll
        for (int f = 0; f < 4; f++) {
            bf16x8 qfr[2];
#pragma unroll
            for (int ks = 0; ks < 2; ks++) qfr[ks] = ldswz(p0, f * 16 + r16, ks, q);
            f32x4 st[2] = {};
#pragma unroll
            for (int jf = 0; jf < 2; jf++)
#pragma unroll
                for (int ks = 0; ks < 2; ks++)
                    st[jf] = __builtin_amdgcn_mfma_f32_16x16x32_bf16(kf[jf][ks], qfr[ks], st[jf], 0, 0, 0);
#pragma unroll
            for (int jf = 0; jf < 2; jf++)
#pragma unroll
                for (int r = 0; r < 4; r++)
                    Zs[jf][r] += exp2fast(st[jf][r] * SCL2);
        }
        __builtin_amdgcn_s_setprio(0);
        char* tp = p0; p0 = p1; p1 = p2; p2 = tp;
    }
    asm volatile("s_waitcnt vmcnt(0)" ::: "memory");
#pragma unroll
    for (int jf = 0; jf < 2; jf++)
#pragma unroll
        for (int r = 0; r < 4; r++) {
            float e = Zs[jf][r];
#pragma unroll
            for (int m = 1; m < 16; m <<= 1) e += __shfl_xor(e, m);
            if (r16 == 0)
                Zpart[((size_t)ihalf * 24 + bh) * SEQ + j0 + jf * 16 + 4 * q + r] = e;
        }
}

// ---------------- scale V^T rows by 1/(Zp0[j]+Zp1[j]) in place ----------------
__global__ __launch_bounds__(256) void k_vscale(uint16_t* __restrict__ VT,
                                                const float* __restrict__ Zpart) {
    size_t t = (size_t)blockIdx.x * 256 + threadIdx.x;
    size_t base = t * 8;
    int rowid = (int)(base >> 11);
    int bh = rowid >> 6;
    int s0 = (int)(base & 2047);
    const float* z0p = Zpart + (size_t)bh * SEQ + s0;
    const float* z1p = Zpart + (size_t)24 * SEQ + (size_t)bh * SEQ + s0;
    float4 a0 = *(const float4*)z0p, a1 = *(const float4*)(z0p + 4);
    float4 b0 = *(const float4*)z1p, b1 = *(const float4*)(z1p + 4);
    ushort4 va = *(ushort4*)(VT + base);
    ushort4 vb = *(ushort4*)(VT + base + 4);
    ushort4 oa, oc;
    oa.x = f2bf(bf2f(va.x) * rcpfast(a0.x + b0.x));
    oa.y = f2bf(bf2f(va.y) * rcpfast(a0.y + b0.y));
    oa.z = f2bf(bf2f(va.z) * rcpfast(a0.z + b0.z));
    oa.w = f2bf(bf2f(va.w) * rcpfast(a0.w + b0.w));
    oc.x = f2bf(bf2f(vb.x) * rcpfast(a1.x + b1.x));
    oc.y = f2bf(bf2f(vb.y) * rcpfast(a1.y + b1.y));
    oc.z = f2bf(bf2f(vb.z) * rcpfast(a1.z + b1.z));
    oc.w = f2bf(bf2f(vb.w) * rcpfast(a1.w + b1.w));
    *(ushort4*)(VT + base) = oa;
    *(ushort4*)(VT + base + 4) = oc;
}

// ---------------- pass 2: Xp[jhalf] = sum_{j in half} 2^(s2) * V'[j] ----------------
// 1D grid 768, XCD-swizzled, rid -> (bh, jhalf, iblk); 4 waves x 32 i.
__global__ __launch_bounds__(256, 3) void k_attn(const uint16_t* __restrict__ Qm,
                                                 const uint16_t* __restrict__ Km,
                                                 const uint16_t* __restrict__ VT,
                                                 float* __restrict__ Xp) {
    __shared__ char lds[3 * 16384];
    const int rid = xcdswz(blockIdx.x, 96);
    const int bh = rid / 32, rem = rid % 32;
    const int jhalf = rem >> 4, iblkidx = rem & 15;
    const int tid = threadIdx.x, lane = tid & 63, w = tid >> 6;
    const int q = lane >> 4, r16 = lane & 15;
    const int b = bh / HEADS, h = bh % HEADS;
    const int iblk = iblkidx * 128;
    const int jbase = jhalf * 1024;
    const uint16_t* Qbase = Qm + (size_t)(b * SEQ + iblk) * DM + h * DK;
    const uint16_t* Kbase = Km + (size_t)(b * SEQ + jbase) * DM + h * DK;
    const uint16_t* VTb = VT + (size_t)bh * DK * SEQ + jbase;
    float* Xout = Xp + (size_t)jhalf * ROWS * DM;

    // prologue: stage this block's Q rows [128][128B] swizzled, extract qf
#pragma unroll
    for (int c = 0; c < 4; c++) {
        int n = c * 256 + tid, row = n >> 3, u = n & 7;
        gload16(Qbase + (size_t)row * DM + ((u ^ (row & 7)) * 8), lds + n * 16);
    }
    asm volatile("s_waitcnt vmcnt(0)" ::: "memory");
    __syncthreads();
    bf16x8 qf[2][2];
#pragma unroll
    for (int ig = 0; ig < 2; ig++)
#pragma unroll
        for (int ks = 0; ks < 2; ks++)
            qf[ig][ks] = ldswz(lds, w * 32 + ig * 16 + r16, ks, q);
    __syncthreads();

    auto stageKV = [&](char* buf, int tt) {
        int js1 = (tt & 15) * 64;
#pragma unroll
        for (int c = 0; c < 2; c++) {
            int n = c * 256 + tid, row = n >> 3, u = n & 7;
            gload16(Kbase + (size_t)(js1 + row) * DM + ((u ^ (row & 7)) * 8), buf + n * 16);
            gload16(VTb + (size_t)row * SEQ + js1 + ((u ^ (row & 7)) * 8), buf + 8192 + n * 16);
        }
    };
    char* p0 = lds;
    char* p1 = lds + 16384;
    char* p2 = lds + 32768;
    stageKV(p0, 0);
    f32x4 xacc[4][2] = {};  // [dc][ig]
    for (int t = 0; t < 16; ++t) {
        stageKV(p1, t + 1);
        asm volatile("s_waitcnt vmcnt(4)" ::: "memory");
        __builtin_amdgcn_sched_barrier(0);
        __builtin_amdgcn_s_barrier();
        __builtin_amdgcn_s_setprio(1);
        const char* Ks = p0;
        const char* Vs = p0 + 8192;
        bf16x8 kf[4][2], vf[4][2];
#pragma unroll
        for (int jf = 0; jf < 4; jf++)
#pragma unroll
            for (int ks = 0; ks < 2; ks++)
                kf[jf][ks] = ldswz(Ks, jf * 16 + r16, ks, q);
#pragma unroll
        for (int dc = 0; dc < 4; dc++)
#pragma unroll
            for (int c = 0; c < 2; c++)
                vf[dc][c] = ldswz(Vs, dc * 16 + r16, c, q);
#pragma unroll
        for (int ig = 0; ig < 2; ig++) {
            f32x4 st[4] = {};
#pragma unroll
            for (int jf = 0; jf < 4; jf++)
#pragma unroll
                for (int ks = 0; ks < 2; ks++)
                    st[jf] = __builtin_amdgcn_mfma_f32_16x16x32_bf16(kf[jf][ks], qf[ig][ks], st[jf], 0, 0, 0);
            bf16x8 pb[2];
#pragma unroll
            for (int c = 0; c < 2; c++) {
                U8 t8;
#pragma unroll
                for (int r = 0; r < 4; r++) {
                    t8.u[r]     = f2bf(exp2fast(st[2 * c][r] * SCL2));
                    t8.u[4 + r] = f2bf(exp2fast(st[2 * c + 1][r] * SCL2));
                }
                pb[c] = t8.v;
            }
#pragma unroll
            for (int dc = 0; dc < 4; dc++)
#pragma unroll
                for (int c = 0; c < 2; c++)
                    xacc[dc][ig] = __builtin_amdgcn_mfma_f32_16x16x32_bf16(vf[dc][c], pb[c], xacc[dc][ig], 0, 0, 0);
        }
        __builtin_amdgcn_s_setprio(0);
        char* tp = p0; p0 = p1; p1 = p2; p2 = tp;
    }
    asm volatile("s_waitcnt vmcnt(0)" ::: "memory");
    __syncthreads();
    // epilogue: per-wave fp32 X^T(d,i) -> X(i,d) via LDS [32 i][264B], then store
    char* xr = lds + w * 8448;
#pragma unroll
    for (int dc = 0; dc < 4; dc++)
#pragma unroll
        for (int ig = 0; ig < 2; ig++)
            *(f32x4*)(xr + (ig * 16 + r16) * 264 + (dc * 16 + 4 * q) * 4) = xacc[dc][ig];
    __syncthreads();
#pragma unroll
    for (int cc = 0; cc < 8; cc++) {
        int uidx = cc * 64 + lane;
        int row = uidx >> 4, seg = uidx & 15;
        *(float4*)(Xout + (size_t)(b * SEQ + iblk + w * 32 + row) * DM + h * DK + seg * 4) =
            *(const float4*)(xr + row * 264 + seg * 16);
    }
}

extern "C" void kernel_launch(void* const* d_in, const int* in_sizes, int n_in,
                              void* d_out, int out_size, void* d_ws, size_t ws_size,
                              hipStream_t stream) {
    const float* query = (const float*)d_in[0];
    const float* key = (const float*)d_in[1];
    const float* value = (const float*)d_in[2];
    const float* Wq = (const float*)d_in[3];
    const float* bq = (const float*)d_in[4];
    const float* Wk = (const float*)d_in[5];
    const float* bk = (const float*)d_in[6];
    const float* Wv = (const float*)d_in[7];
    const float* bv = (const float*)d_in[8];
    const float* Wo = (const float*)d_in[9];
    const float* bo = (const float*)d_in[10];
    float* out = (float*)d_out;
    char* ws = (char*)d_ws;

    const size_t SZ = (size_t)ROWS * DM * 2;         // 6.29 MB bf16 tensor
    const size_t WSZ = (size_t)DM * DM * 2;          // 1.18 MB bf16 weight
    const size_t XSZ = (size_t)ROWS * DM * 4;        // 12.58 MB fp32 partial
    uint16_t* Qm = (uint16_t*)(ws + 0 * SZ);
    uint16_t* Km = (uint16_t*)(ws + 1 * SZ);
    uint16_t* VT = (uint16_t*)(ws + 2 * SZ);
    uint16_t* Wqt = (uint16_t*)(ws + 3 * SZ);
    uint16_t* Wkt = (uint16_t*)(ws + 3 * SZ + WSZ);
    uint16_t* Wvt = (uint16_t*)(ws + 3 * SZ + 2 * WSZ);
    uint16_t* Wot = (uint16_t*)(ws + 3 * SZ + 3 * WSZ);
    float* Zpart = (float*)(ws + 3 * SZ + 4 * WSZ);  // [2][24][2048] f32
    char* xbase = ws + 3 * SZ + 4 * WSZ + 2 * 24 * SEQ * 4;
    float* Xp0 = (float*)xbase;
    float* Xp1 = (float*)(xbase + XSZ);

    k_transpose<<<dim3(24, 24, 4), 256, 0, stream>>>(Wq, Wk, Wv, Wo, Wqt, Wkt, Wvt, Wot);
    k_gemm_qkv<<<dim3(576), 256, 0, stream>>>(query, key, value, Wqt, bq, bk, bv, Qm, Km, VT);
    k_stats<<<dim3(768), 256, 0, stream>>>(Qm, Km, Zpart);
    k_vscale<<<dim3(1536), 256, 0, stream>>>(VT, Zpart);
    k_attn<<<dim3(768), 256, 0, stream>>>(Qm, Km, VT, Xp0);
    k_gemm_o<<<dim3(192), 256, 0, stream>>>(Xp0, Xp1, Wot, bo, out);
}